// Round 9
// baseline (144.957 us; speedup 1.0000x reference)
//
#include <hip/hip_runtime.h>
#include <math.h>

typedef unsigned int u32;
typedef unsigned short u16;
typedef unsigned long long u64;

#define PRE_NMS 6000
#define NBLK    94          /* ceil(6000/64) rank-bitmap words */
#define KMAX    640         /* group capacity (E[K]~375) */
#define MSTRIDE 11          /* mask row stride, > KMAX/64 */
#define MAXW    10          /* max 64-blocks per group */
#define MTILE   (MAXW * MAXW)
#define FINEB   8192        /* [0.5,1) buckets, 2^10 ulp each */
#define LOWB    8064        /* [0,0.5) buckets, bits>>17 */
#define NHB     128         /* hist blocks / low-partial copies */
#define CANDMAX 16384
#define NGRP    24
#define FLOOR_BITS 0x3F000000u   /* 0.5f */

/* ws byte offsets ([CTR|FINEH|BCNT|GBITS] contiguous -> one memset) */
#define CTR_OFF    0          /* 64 u32 -> 256 ([0]=M [1]=pivot [2]=ticket) */
#define FINEH_OFF  256        /* 8192 u32 -> 33024 */
#define BCNT_OFF   33024      /* 16384 u32 -> 98560 */
#define GBITS_OFF  98560      /* 24*192 u32 -> 116992 */
#define ZERO_LEN   116992     /* bytes from 0 */
#define CAND_OFF   116992     /* 16384 u64 -> 248064 */
#define BOXR_OFF   248064     /* 6016 float4 -> 344320 */
#define KG_OFF     344320     /* 64 u32 -> 344576 */
#define GRANKG_OFF 344576     /* 24*640 u32 -> 406016 */
#define BOXG_OFF   406016     /* 24*640 float4 -> 651776 */
#define AREAG_OFF  651776     /* 24*640 f32 -> 713216 */
#define MASKG_OFF  713216     /* 24*640*11 u64 -> 2064896 */
#define BASE_OFF   2064896    /* 16384 u32 -> 2130432 */
#define PART_OFF   2130432    /* 128 x 8064 u32 (low-range, fallback) */

/* bucket index in [0,16384): fine fb in [0,8192), low 8192+lb */
__device__ __forceinline__ u32 bucket_of(u32 bits) {
    if (bits >= FLOOR_BITS) {
        u32 fb = (bits - FLOOR_BITS) >> 10; if (fb > FINEB - 1) fb = FINEB - 1;
        return fb;
    }
    return 8192u + (bits >> 17);
}

/* 1: histogram + fused pivot (last-block-done ticket).
   Fine range merged into global fineh via device-scope atomics; low range
   kept as per-block partials (fallback only). The last block to finish
   runs the exact suffix-scan pivot, reusing its LDS. */
__global__ __launch_bounds__(1024) void histpivot_kernel(const float4* __restrict__ probs4,
                                                         u32* __restrict__ fineh,
                                                         u32* __restrict__ partials,
                                                         u32* __restrict__ ctr,
                                                         u32* __restrict__ base,
                                                         int n_prop) {
    __shared__ u32 hf[FINEB];      /* 32 KB */
    __shared__ u32 hl[2][LOWB];    /* 63 KB */
    __shared__ u32 s_tick;
    int t = threadIdx.x;
    for (int i = t; i < FINEB; i += 1024) hf[i] = 0u;
    for (int i = t; i < 2 * LOWB; i += 1024) ((u32*)hl)[i] = 0u;
    __syncthreads();
    u32* l = hl[(t >> 6) & 1];
    int nq = n_prop >> 2;
    int idx = blockIdx.x * 1024 + t;
    int stride = gridDim.x * 1024;
    for (int q = idx; q < nq; q += stride) {
        float4 a = probs4[3 * q + 0];
        float4 b = probs4[3 * q + 1];
        float4 c = probs4[3 * q + 2];
        float vs[8] = {a.y, a.z, b.x, b.y, b.w, c.x, c.z, c.w};
        #pragma unroll
        for (int e = 0; e < 8; ++e) {
            u32 bits = __float_as_uint(vs[e]);
            if (bits >= FLOOR_BITS) {
                u32 fb = (bits - FLOOR_BITS) >> 10; if (fb >= FINEB) fb = FINEB - 1;
                atomicAdd(&hf[fb], 1u);
            } else {
                atomicAdd(&l[bits >> 17], 1u);
            }
        }
    }
    __syncthreads();
    for (int b = t; b < FINEB; b += 1024) {
        u32 v = hf[b];
        if (v) atomicAdd(&fineh[b], v);
    }
    u32* outp = partials + blockIdx.x * LOWB;
    for (int b = t; b < LOWB; b += 1024) outp[b] = hl[0][b] + hl[1][b];
    __syncthreads();                       /* all block mem ops drained */

    if (t == 0) {
        __threadfence();                   /* release before ticket */
        s_tick = atomicAdd(&ctr[2], 1u);
    }
    __syncthreads();
    if (s_tick != (u32)gridDim.x - 1u) return;

    /* ---- elected block: exact pivot scan (identical semantics) ---- */
    __threadfence();                       /* acquire */
    u32* fh = hf;                          /* reuse LDS */
    u32* sd = hl[0];
    for (int b = t; b < FINEB; b += 1024) fh[b] = fineh[b];
    __syncthreads();
    int hi = FINEB - 1 - 8 * t;
    u32 L = 0;
    #pragma unroll
    for (int e = 0; e < 8; ++e) L += fh[hi - e];
    sd[t] = L;
    __syncthreads();
    for (int off = 1; off < 1024; off <<= 1) {
        u32 x = (t >= off) ? sd[t - off] : 0u;
        __syncthreads();
        sd[t] += x;
        __syncthreads();
    }
    u32 incl = sd[t], excl = incl - L;
    u32 fineTotal = sd[1023];
    {
        u32 run = excl;
        #pragma unroll
        for (int e = 0; e < 8; ++e) {
            int fb = hi - e;
            base[fb] = run;
            u32 c = fh[fb];
            if (run < (u32)PRE_NMS && run + c >= (u32)PRE_NMS) {
                ctr[1] = FLOOR_BITS + ((u32)fb << 10);
                u32 m = run + c; if (m > (u32)CANDMAX) m = (u32)CANDMAX;
                ctr[0] = m;
            }
            run += c;
        }
    }
    if (fineTotal >= (u32)PRE_NMS) return;

    /* fallback (never expected): reduce low partials, continue scan */
    u32 rem = (u32)PRE_NMS - fineTotal;
    __syncthreads();
    for (int b = t; b < FINEB; b += 1024) {
        u32 s = 0;
        if (b < LOWB) {
            for (int k = 0; k < NHB; ++k) s += partials[k * LOWB + b];
        }
        fh[b] = s;
    }
    __syncthreads();
    L = 0;
    #pragma unroll
    for (int e = 0; e < 8; ++e) L += fh[hi - e];
    sd[t] = L;
    __syncthreads();
    for (int off = 1; off < 1024; off <<= 1) {
        u32 x = (t >= off) ? sd[t - off] : 0u;
        __syncthreads();
        sd[t] += x;
        __syncthreads();
    }
    incl = sd[t]; excl = incl - L;
    {
        u32 run = excl;
        #pragma unroll
        for (int e = 0; e < 8; ++e) {
            int lb = hi - e;
            base[8192 + lb] = fineTotal + run;
            u32 c = fh[lb];
            if (run < rem && run + c >= rem) {
                ctr[1] = ((u32)lb) << 17;
                u32 m = fineTotal + run + c; if (m > (u32)CANDMAX) m = (u32)CANDMAX;
                ctr[0] = m;
            }
            run += c;
        }
    }
}

/* 2: scatter-compact: candidate -> its bucket's contiguous slot range. */
__global__ __launch_bounds__(256) void scatter_kernel(const float4* __restrict__ probs4,
                                                      const u32* __restrict__ ctr,
                                                      const u32* __restrict__ base,
                                                      u32* __restrict__ bcnt,
                                                      u64* __restrict__ cand,
                                                      int n_prop) {
    u32 pivot = ctr[1];
    int nq = n_prop >> 2;
    int idx = blockIdx.x * 256 + threadIdx.x;
    int stride = gridDim.x * 256;
    for (int q = idx; q < nq; q += stride) {
        float4 a = probs4[3 * q + 0];
        float4 b = probs4[3 * q + 1];
        float4 c = probs4[3 * q + 2];
        float vs[8] = {a.y, a.z, b.x, b.y, b.w, c.x, c.z, c.w};
        #pragma unroll
        for (int e = 0; e < 8; ++e) {
            u32 bits = __float_as_uint(vs[e]);
            if (bits >= pivot) {
                u32 bk = bucket_of(bits);
                u32 off = atomicAdd(&bcnt[bk], 1u);
                u32 slot = base[bk] + off;
                u32 i = (u32)(8 * q + e);
                if (slot < (u32)CANDMAX) cand[slot] = ((u64)bits << 32) | (u64)(~i);
            }
        }
    }
}

/* 3: local rank (bucket base + count-greater among tiny bucket group) + decode. */
__global__ __launch_bounds__(256) void rankdecode_kernel(const u64* __restrict__ cand,
                                                         const u32* __restrict__ ctr,
                                                         const u32* __restrict__ base,
                                                         const u32* __restrict__ bcnt,
                                                         const float4* __restrict__ deltas4,
                                                         const float4* __restrict__ anchors4,
                                                         float4* __restrict__ boxr,
                                                         u32* __restrict__ gbits,
                                                         float* __restrict__ out,
                                                         int n_anch) {
    u32 M = ctr[0]; if (M > (u32)CANDMAX) M = (u32)CANDMAX;
    u32 i = blockIdx.x * 256 + threadIdx.x;
    if (i >= M) return;
    u64 key = cand[i];
    u32 bits = (u32)(key >> 32);
    u32 bk = bucket_of(bits);
    u32 b0 = base[bk];
    u32 n = bcnt[bk];
    u32 r = b0;
    if (n > 1) {
        u32 end = b0 + n; if (end > M) end = M;
        u32 cnt = 0;
        for (u32 j = b0; j < end; ++j) cnt += (cand[j] > key) ? 1u : 0u;
        r = b0 + cnt;
    }
    if (r >= (u32)PRE_NMS) return;
    u32 flat = ~((u32)key);
    int p = (int)(flat >> 1);
    int cls = (int)(flat & 1u) + 1;
    int b = p / n_anch;
    int g = b * 3 + cls;
    int aidx = p - b * n_anch;
    float score = __uint_as_float(bits);
    float4 a = anchors4[aidx];
    float4 d = deltas4[p];
    float d0 = d.x * 0.1f, d1 = d.y * 0.1f, d2 = d.z * 0.2f, d3 = d.w * 0.2f;
    float y1 = a.x * (1.0f / 512.0f), x1 = a.y * (1.0f / 512.0f);
    float y2 = a.z * (1.0f / 512.0f), x2 = a.w * (1.0f / 512.0f);
    float h = y2 - y1, w = x2 - x1;
    float cy = y1 + 0.5f * h + d0 * h;
    float cx = x1 + 0.5f * w + d1 * w;
    h = h * expf(d2);
    w = w * expf(d3);
    float ry1 = (cy - 0.5f * h) * 512.0f;
    float rx1 = (cx - 0.5f * w) * 512.0f;
    float ry2 = (cy - 0.5f * h + h) * 512.0f;
    float rx2 = (cx - 0.5f * w + w) * 512.0f;
    ry1 = fminf(fmaxf(ry1, 0.0f), 512.0f);
    rx1 = fminf(fmaxf(rx1, 0.0f), 512.0f);
    ry2 = fminf(fmaxf(ry2, 0.0f), 512.0f);
    rx2 = fminf(fmaxf(rx2, 0.0f), 512.0f);
    out[r * 6 + 0] = ry1;
    out[r * 6 + 1] = rx1;
    out[r * 6 + 2] = ry2;
    out[r * 6 + 3] = rx2;
    out[r * 6 + 4] = score;
    out[r * 6 + 5] = 1.0f;               /* default keep; greedy overwrites */
    out[PRE_NMS * 6 + r] = (float)cls;
    out[PRE_NMS * 7 + r] = (float)b;
    boxr[r] = make_float4(ry1, rx1, ry2, rx2);
    atomicOr(&gbits[g * 192 + (r >> 5)], 1u << (r & 31));
}

/* 4: per-group prep: bitmap prefix -> rank-ordered box table in global
   (sentinel-padded to KMAX), grank table, K. */
__global__ __launch_bounds__(512) void prep_kernel(const u32* __restrict__ gbits,
                                                   const float4* __restrict__ boxr,
                                                   u32* __restrict__ kg,
                                                   u32* __restrict__ grankg,
                                                   float4* __restrict__ boxg,
                                                   float* __restrict__ areag) {
    __shared__ int bpre[96];
    __shared__ u16 grankS[KMAX];
    __shared__ int sK;
    int g = blockIdx.x, t = threadIdx.x, lane = t & 63, wv = t >> 6;
    const u32* rb32 = gbits + g * 192;

    if (t < 64) {
        u64 w0 = (u64)rb32[2 * lane] | ((u64)rb32[2 * lane + 1] << 32);
        u64 w1 = (lane < NBLK - 64)
                 ? ((u64)rb32[128 + 2 * lane] | ((u64)rb32[129 + 2 * lane] << 32)) : 0ull;
        int c0 = (int)__popcll(w0), c1 = (int)__popcll(w1);
        int i0 = c0, i1 = c1;
        #pragma unroll
        for (int off = 1; off < 64; off <<= 1) {
            int a = __shfl_up(i0, off); if (lane >= off) i0 += a;
            int b = __shfl_up(i1, off); if (lane >= off) i1 += b;
        }
        int tot0 = __shfl(i0, 63), tot1 = __shfl(i1, 63);
        bpre[lane] = i0 - c0;
        if (lane < 32) bpre[64 + lane] = tot0 + ((lane < NBLK - 64) ? (i1 - c1) : 0);
        if (lane == 0) { sK = tot0 + tot1; kg[g] = (u32)(tot0 + tot1); }
    }
    __syncthreads();
    int K = sK;
    if (K == 0) return;
    int Kc = (K < KMAX) ? K : KMAX;

    for (int blk = wv; blk < NBLK; blk += 8) {
        u64 wmask = (u64)rb32[2 * blk] | ((u64)rb32[2 * blk + 1] << 32);
        if ((wmask >> lane) & 1ull) {
            int pos = bpre[blk] + (int)__popcll(wmask & ((1ull << lane) - 1ull));
            if (pos < KMAX) grankS[pos] = (u16)((blk << 6) | lane);
        }
    }
    __syncthreads();

    float4* bg = boxg + g * KMAX;
    float*  ag = areag + g * KMAX;
    u32*    gr = grankg + g * KMAX;
    for (int m = t; m < KMAX; m += 512) {
        if (m < Kc) {
            int r = grankS[m];
            float4 bb = boxr[r];
            bg[m] = bb;
            ag[m] = (bb.z - bb.x + 1.0f) * (bb.w - bb.y + 1.0f);
            gr[m] = (u32)r;
        } else {
            bg[m] = make_float4(-3e30f, -3e30f, -3e30f, -3e30f);
            ag[m] = 3e38f;
        }
    }
}

/* 5: register-resident 64x64 IoU tiles, one 1-wave block per (group, tile). */
__global__ __launch_bounds__(64) void mask_kernel(const u32* __restrict__ kg,
                                                  const float4* __restrict__ boxg,
                                                  const float* __restrict__ areag,
                                                  u64* __restrict__ maskg) {
    int g = blockIdx.y;
    u32 K = kg[g];
    if (K == 0u) return;
    int Kc = (K < (u32)KMAX) ? (int)K : KMAX;
    int W = (Kc + 63) >> 6;
    int u = blockIdx.x;
    int c = u / MAXW, rbk = u % MAXW;
    if (c >= W || rbk >= W) return;
    int lane = threadIdx.x;
    int r = rbk * 64 + lane;
    u64* mg = maskg + (size_t)g * (KMAX * MSTRIDE);
    if (rbk > c) { mg[r * MSTRIDE + c] = 0ull; return; }
    int j0 = c << 6;
    const float4* bg = boxg + g * KMAX;
    const float*  ag = areag + g * KMAX;
    float4 rb = bg[r];
    float  ra = ag[r];
    float4 cb = bg[j0 + lane];
    float  ca = ag[j0 + lane];
    u64 word = 0ull;
    #pragma unroll 8
    for (int q = 0; q < 64; ++q) {
        float cbx = __shfl(cb.x, q);
        float cby = __shfl(cb.y, q);
        float cbz = __shfl(cb.z, q);
        float cbw = __shfl(cb.w, q);
        float cav = __shfl(ca, q);
        float ih = fminf(rb.z, cbz) - fmaxf(rb.x, cbx) + 1.0f;
        float iw = fminf(rb.w, cbw) - fmaxf(rb.y, cby) + 1.0f;
        ih = fmaxf(ih, 0.0f); iw = fmaxf(iw, 0.0f);
        /* iou>=0.5 <=> 3*inter >= ai+aj */
        bool o = (3.0f * ih * iw >= ra + cav) && ((j0 + q) > r);
        if (o) word |= (1ull << q);
    }
    mg[r * MSTRIDE + c] = word;
}

/* 6: per-group serial greedy. Stage mask L2->LDS coalesced, then chunk-8 scan. */
__global__ __launch_bounds__(512) void greedy_kernel(const u32* __restrict__ kg,
                                                     const u32* __restrict__ grankg,
                                                     const u64* __restrict__ maskg,
                                                     float* __restrict__ out) {
    __shared__ u64 maskm[KMAX * MSTRIDE + 64];   /* 56.8 KB */
    __shared__ u16 grank[KMAX];
    int g = blockIdx.x, t = threadIdx.x, lane = t & 63;
    u32 K = kg[g];
    if (K == 0u) return;
    int Kc = (K < (u32)KMAX) ? (int)K : KMAX;
    int W = (Kc + 63) >> 6;
    const u64* mg = maskg + (size_t)g * (KMAX * MSTRIDE);
    int nw = Kc * MSTRIDE;
    for (int m = t; m < nw; m += 512) maskm[m] = mg[m];
    for (int m = nw + t; m < nw + 64; m += 512) maskm[m] = 0ull;
    for (int m = t; m < Kc; m += 512) grank[m] = (u16)grankg[g * KMAX + m];
    __syncthreads();

    if (t >= 64) return;
    u64 remv = 0ull;
    for (int w = 0; w < W; ++w) {
        int r0 = w << 6;
        int rend = Kc - r0; if (rend > 64) rend = 64;
        u64 curw = __shfl(remv, w);
        u64 kb = 0ull;
        for (int b0 = 0; b0 < rend; b0 += 8) {
            int n = rend - b0; if (n > 8) n = 8;
            u64 mrow[8], dg[8];
            #pragma unroll
            for (int j = 0; j < 8; ++j) {
                int rr = r0 + b0 + ((j < n) ? j : 0);
                mrow[j] = maskm[rr * MSTRIDE + lane];   /* +64 pad covers overrun */
                dg[j]   = maskm[rr * MSTRIDE + w];      /* uniform: broadcast */
            }
            #pragma unroll
            for (int j = 0; j < 8; ++j) {
                if (j < n) {
                    int b = b0 + j;
                    u64 km = ((curw >> b) & 1ull) ? 0ull : ~0ull;
                    curw |= dg[j] & km;
                    remv |= mrow[j] & km;
                    kb |= km & (1ull << b);
                }
            }
        }
        if (lane < rend)
            out[(int)grank[r0 + lane] * 6 + 5] = ((kb >> lane) & 1ull) ? 1.0f : 0.0f;
    }
}

extern "C" void kernel_launch(void* const* d_in, const int* in_sizes, int n_in,
                              void* d_out, int out_size, void* d_ws, size_t ws_size,
                              hipStream_t stream) {
    const float*  probs    = (const float*)d_in[0];
    const float4* deltas4  = (const float4*)d_in[1];
    const float4* anchors4 = (const float4*)d_in[2];
    int n_prop = in_sizes[1] / 4;   /* 522240 */
    int n_anch = in_sizes[2] / 4;   /* 65280  */

    char* ws = (char*)d_ws;
    u32* ctr      = (u32*)(ws + CTR_OFF);
    u32* fineh    = (u32*)(ws + FINEH_OFF);
    u32* bcnt     = (u32*)(ws + BCNT_OFF);
    u32* gbits    = (u32*)(ws + GBITS_OFF);
    u64* cand     = (u64*)(ws + CAND_OFF);
    float4* boxr  = (float4*)(ws + BOXR_OFF);
    u32* kg       = (u32*)(ws + KG_OFF);
    u32* grankg   = (u32*)(ws + GRANKG_OFF);
    float4* boxg  = (float4*)(ws + BOXG_OFF);
    float* areag  = (float*)(ws + AREAG_OFF);
    u64* maskg    = (u64*)(ws + MASKG_OFF);
    u32* base     = (u32*)(ws + BASE_OFF);
    u32* partials = (u32*)(ws + PART_OFF);
    float* out    = (float*)d_out;

    hipMemsetAsync(ws, 0, ZERO_LEN, stream);
    histpivot_kernel<<<NHB, 1024, 0, stream>>>((const float4*)probs, fineh, partials,
                                               ctr, base, n_prop);
    scatter_kernel<<<512, 256, 0, stream>>>((const float4*)probs, ctr, base, bcnt,
                                            cand, n_prop);
    rankdecode_kernel<<<CANDMAX / 256, 256, 0, stream>>>(cand, ctr, base, bcnt,
                                                         deltas4, anchors4,
                                                         boxr, gbits, out, n_anch);
    prep_kernel<<<NGRP, 512, 0, stream>>>(gbits, boxr, kg, grankg, boxg, areag);
    mask_kernel<<<dim3(MTILE, NGRP), 64, 0, stream>>>(kg, boxg, areag, maskg);
    greedy_kernel<<<NGRP, 512, 0, stream>>>(kg, grankg, maskg, out);
}

// Round 10
// 140.099 us; speedup vs baseline: 1.0347x; 1.0347x over previous
//
#include <hip/hip_runtime.h>
#include <math.h>

typedef unsigned int u32;
typedef unsigned short u16;
typedef unsigned long long u64;

#define PRE_NMS 6000
#define NBLK    94          /* ceil(6000/64) rank-bitmap words */
#define KMAX    640         /* group capacity (E[K]~375) */
#define MSTRIDE 11          /* mask row stride, > KMAX/64 */
#define MAXW    10          /* max 64-blocks per group */
#define MTILE   (MAXW * MAXW)
#define FINEB   8192        /* [0.5,1) buckets, 2^10 ulp each */
#define LOWB    8064        /* [0,0.5) buckets, bits>>17 */
#define NHB     64          /* hist blocks */
#define CANDMAX 16384
#define NGRP    24
#define FLOOR_BITS 0x3F000000u   /* 0.5f */

/* ws byte offsets ([CTR|FINEH|BCNT|GBITS] contiguous -> one memset) */
#define CTR_OFF    0          /* 64 u32 -> 256 ([0]=M [1]=pivot [2]=ticket) */
#define FINEH_OFF  256        /* 8192 u32 -> 33024 */
#define BCNT_OFF   33024      /* 16384 u32 -> 98560 */
#define GBITS_OFF  98560      /* 24*192 u32 -> 116992 */
#define ZERO_LEN   116992     /* bytes from 0 */
#define CAND_OFF   116992     /* 16384 u64 -> 248064 */
#define BOXR_OFF   248064     /* 6016 float4 -> 344320 */
#define KG_OFF     344320     /* 64 u32 -> 344576 */
#define GRANKG_OFF 344576     /* 24*640 u32 -> 406016 */
#define BOXG_OFF   406016     /* 24*640 float4 -> 651776 */
#define AREAG_OFF  651776     /* 24*640 f32 -> 713216 */
#define MASKG_OFF  713216     /* 24*640*11 u64 -> 2064896 */
#define BASE_OFF   2064896    /* 16384 u32 -> 2130432 */

/* bucket index in [0,16384): fine fb in [0,8192), low 8192+lb */
__device__ __forceinline__ u32 bucket_of(u32 bits) {
    if (bits >= FLOOR_BITS) {
        u32 fb = (bits - FLOOR_BITS) >> 10; if (fb > FINEB - 1) fb = FINEB - 1;
        return fb;
    }
    return 8192u + (bits >> 17);
}

/* 1: fine-range-only histogram + fused pivot (last-block-done ticket).
   Values < 0.5 are NOT histogrammed in the hot path (they can't matter:
   fineTotal >= 6000 in practice). The elected block runs the exact
   suffix-scan pivot; if fineTotal < 6000 (never expected) it re-reads
   probs itself and histograms the low range single-block. */
__global__ __launch_bounds__(1024) void histpivot_kernel(const float4* __restrict__ probs4,
                                                         u32* __restrict__ fineh,
                                                         u32* __restrict__ ctr,
                                                         u32* __restrict__ base,
                                                         int n_prop) {
    __shared__ u32 hf[FINEB];      /* 32 KB */
    __shared__ u32 sd[1024];       /* 4 KB  */
    __shared__ u32 hlow[LOWB];     /* 31.5 KB (fallback only) */
    __shared__ u32 s_tick;
    int t = threadIdx.x;
    for (int i = t; i < FINEB; i += 1024) hf[i] = 0u;
    __syncthreads();
    int nq = n_prop >> 2;
    int idx = blockIdx.x * 1024 + t;
    int stride = gridDim.x * 1024;
    for (int q = idx; q < nq; q += stride) {
        float4 a = probs4[3 * q + 0];
        float4 b = probs4[3 * q + 1];
        float4 c = probs4[3 * q + 2];
        float vs[8] = {a.y, a.z, b.x, b.y, b.w, c.x, c.z, c.w};
        #pragma unroll
        for (int e = 0; e < 8; ++e) {
            u32 bits = __float_as_uint(vs[e]);
            if (bits >= FLOOR_BITS) {
                u32 fb = (bits - FLOOR_BITS) >> 10; if (fb >= FINEB) fb = FINEB - 1;
                atomicAdd(&hf[fb], 1u);
            }
        }
    }
    __syncthreads();
    for (int b = t; b < FINEB; b += 1024) {
        u32 v = hf[b];
        if (v) atomicAdd(&fineh[b], v);
    }
    __syncthreads();                       /* all block mem ops drained */

    if (t == 0) {
        __threadfence();                   /* release before ticket */
        s_tick = atomicAdd(&ctr[2], 1u);
    }
    __syncthreads();
    if (s_tick != (u32)gridDim.x - 1u) return;

    /* ---- elected block: exact pivot scan (identical semantics) ---- */
    __threadfence();                       /* acquire */
    u32* fh = hf;                          /* reuse LDS */
    for (int b = t; b < FINEB; b += 1024) fh[b] = fineh[b];
    __syncthreads();
    int hi = FINEB - 1 - 8 * t;
    u32 L = 0;
    #pragma unroll
    for (int e = 0; e < 8; ++e) L += fh[hi - e];
    sd[t] = L;
    __syncthreads();
    for (int off = 1; off < 1024; off <<= 1) {
        u32 x = (t >= off) ? sd[t - off] : 0u;
        __syncthreads();
        sd[t] += x;
        __syncthreads();
    }
    u32 incl = sd[t], excl = incl - L;
    u32 fineTotal = sd[1023];
    {
        u32 run = excl;
        #pragma unroll
        for (int e = 0; e < 8; ++e) {
            int fb = hi - e;
            base[fb] = run;
            u32 c = fh[fb];
            if (run < (u32)PRE_NMS && run + c >= (u32)PRE_NMS) {
                ctr[1] = FLOOR_BITS + ((u32)fb << 10);
                u32 m = run + c; if (m > (u32)CANDMAX) m = (u32)CANDMAX;
                ctr[0] = m;
            }
            run += c;
        }
    }
    if (fineTotal >= (u32)PRE_NMS) return;

    /* fallback (never expected): this block re-reads probs and histograms
       the low range itself, then continues the exact scan. */
    u32 rem = (u32)PRE_NMS - fineTotal;
    __syncthreads();
    for (int i = t; i < LOWB; i += 1024) hlow[i] = 0u;
    __syncthreads();
    for (int q = t; q < nq; q += 1024) {
        float4 a = probs4[3 * q + 0];
        float4 b = probs4[3 * q + 1];
        float4 c = probs4[3 * q + 2];
        float vs[8] = {a.y, a.z, b.x, b.y, b.w, c.x, c.z, c.w};
        #pragma unroll
        for (int e = 0; e < 8; ++e) {
            u32 bits = __float_as_uint(vs[e]);
            if (bits < FLOOR_BITS) atomicAdd(&hlow[bits >> 17], 1u);
        }
    }
    __syncthreads();
    for (int b = t; b < FINEB; b += 1024) fh[b] = (b < LOWB) ? hlow[b] : 0u;
    __syncthreads();
    L = 0;
    #pragma unroll
    for (int e = 0; e < 8; ++e) L += fh[hi - e];
    sd[t] = L;
    __syncthreads();
    for (int off = 1; off < 1024; off <<= 1) {
        u32 x = (t >= off) ? sd[t - off] : 0u;
        __syncthreads();
        sd[t] += x;
        __syncthreads();
    }
    incl = sd[t]; excl = incl - L;
    {
        u32 run = excl;
        #pragma unroll
        for (int e = 0; e < 8; ++e) {
            int lb = hi - e;
            base[8192 + lb] = fineTotal + run;
            u32 c = fh[lb];
            if (run < rem && run + c >= rem) {
                ctr[1] = ((u32)lb) << 17;
                u32 m = fineTotal + run + c; if (m > (u32)CANDMAX) m = (u32)CANDMAX;
                ctr[0] = m;
            }
            run += c;
        }
    }
}

/* 2: scatter-compact: candidate -> its bucket's contiguous slot range. */
__global__ __launch_bounds__(256) void scatter_kernel(const float4* __restrict__ probs4,
                                                      const u32* __restrict__ ctr,
                                                      const u32* __restrict__ base,
                                                      u32* __restrict__ bcnt,
                                                      u64* __restrict__ cand,
                                                      int n_prop) {
    u32 pivot = ctr[1];
    int nq = n_prop >> 2;
    int idx = blockIdx.x * 256 + threadIdx.x;
    int stride = gridDim.x * 256;
    for (int q = idx; q < nq; q += stride) {
        float4 a = probs4[3 * q + 0];
        float4 b = probs4[3 * q + 1];
        float4 c = probs4[3 * q + 2];
        float vs[8] = {a.y, a.z, b.x, b.y, b.w, c.x, c.z, c.w};
        #pragma unroll
        for (int e = 0; e < 8; ++e) {
            u32 bits = __float_as_uint(vs[e]);
            if (bits >= pivot) {
                u32 bk = bucket_of(bits);
                u32 off = atomicAdd(&bcnt[bk], 1u);
                u32 slot = base[bk] + off;
                u32 i = (u32)(8 * q + e);
                if (slot < (u32)CANDMAX) cand[slot] = ((u64)bits << 32) | (u64)(~i);
            }
        }
    }
}

/* 3: local rank (bucket base + count-greater among tiny bucket group) + decode. */
__global__ __launch_bounds__(256) void rankdecode_kernel(const u64* __restrict__ cand,
                                                         const u32* __restrict__ ctr,
                                                         const u32* __restrict__ base,
                                                         const u32* __restrict__ bcnt,
                                                         const float4* __restrict__ deltas4,
                                                         const float4* __restrict__ anchors4,
                                                         float4* __restrict__ boxr,
                                                         u32* __restrict__ gbits,
                                                         float* __restrict__ out,
                                                         int n_anch) {
    u32 M = ctr[0]; if (M > (u32)CANDMAX) M = (u32)CANDMAX;
    u32 i = blockIdx.x * 256 + threadIdx.x;
    if (i >= M) return;
    u64 key = cand[i];
    u32 bits = (u32)(key >> 32);
    u32 bk = bucket_of(bits);
    u32 b0 = base[bk];
    u32 n = bcnt[bk];
    u32 r = b0;
    if (n > 1) {
        u32 end = b0 + n; if (end > M) end = M;
        u32 cnt = 0;
        for (u32 j = b0; j < end; ++j) cnt += (cand[j] > key) ? 1u : 0u;
        r = b0 + cnt;
    }
    if (r >= (u32)PRE_NMS) return;
    u32 flat = ~((u32)key);
    int p = (int)(flat >> 1);
    int cls = (int)(flat & 1u) + 1;
    int b = p / n_anch;
    int g = b * 3 + cls;
    int aidx = p - b * n_anch;
    float score = __uint_as_float(bits);
    float4 a = anchors4[aidx];
    float4 d = deltas4[p];
    float d0 = d.x * 0.1f, d1 = d.y * 0.1f, d2 = d.z * 0.2f, d3 = d.w * 0.2f;
    float y1 = a.x * (1.0f / 512.0f), x1 = a.y * (1.0f / 512.0f);
    float y2 = a.z * (1.0f / 512.0f), x2 = a.w * (1.0f / 512.0f);
    float h = y2 - y1, w = x2 - x1;
    float cy = y1 + 0.5f * h + d0 * h;
    float cx = x1 + 0.5f * w + d1 * w;
    h = h * expf(d2);
    w = w * expf(d3);
    float ry1 = (cy - 0.5f * h) * 512.0f;
    float rx1 = (cx - 0.5f * w) * 512.0f;
    float ry2 = (cy - 0.5f * h + h) * 512.0f;
    float rx2 = (cx - 0.5f * w + w) * 512.0f;
    ry1 = fminf(fmaxf(ry1, 0.0f), 512.0f);
    rx1 = fminf(fmaxf(rx1, 0.0f), 512.0f);
    ry2 = fminf(fmaxf(ry2, 0.0f), 512.0f);
    rx2 = fminf(fmaxf(rx2, 0.0f), 512.0f);
    out[r * 6 + 0] = ry1;
    out[r * 6 + 1] = rx1;
    out[r * 6 + 2] = ry2;
    out[r * 6 + 3] = rx2;
    out[r * 6 + 4] = score;
    out[r * 6 + 5] = 1.0f;               /* default keep; greedy overwrites */
    out[PRE_NMS * 6 + r] = (float)cls;
    out[PRE_NMS * 7 + r] = (float)b;
    boxr[r] = make_float4(ry1, rx1, ry2, rx2);
    atomicOr(&gbits[g * 192 + (r >> 5)], 1u << (r & 31));
}

/* 4: per-group prep: bitmap prefix -> rank-ordered box table in global
   (sentinel-padded to KMAX), grank table, K. */
__global__ __launch_bounds__(512) void prep_kernel(const u32* __restrict__ gbits,
                                                   const float4* __restrict__ boxr,
                                                   u32* __restrict__ kg,
                                                   u32* __restrict__ grankg,
                                                   float4* __restrict__ boxg,
                                                   float* __restrict__ areag) {
    __shared__ int bpre[96];
    __shared__ u16 grankS[KMAX];
    __shared__ int sK;
    int g = blockIdx.x, t = threadIdx.x, lane = t & 63, wv = t >> 6;
    const u32* rb32 = gbits + g * 192;

    if (t < 64) {
        u64 w0 = (u64)rb32[2 * lane] | ((u64)rb32[2 * lane + 1] << 32);
        u64 w1 = (lane < NBLK - 64)
                 ? ((u64)rb32[128 + 2 * lane] | ((u64)rb32[129 + 2 * lane] << 32)) : 0ull;
        int c0 = (int)__popcll(w0), c1 = (int)__popcll(w1);
        int i0 = c0, i1 = c1;
        #pragma unroll
        for (int off = 1; off < 64; off <<= 1) {
            int a = __shfl_up(i0, off); if (lane >= off) i0 += a;
            int b = __shfl_up(i1, off); if (lane >= off) i1 += b;
        }
        int tot0 = __shfl(i0, 63), tot1 = __shfl(i1, 63);
        bpre[lane] = i0 - c0;
        if (lane < 32) bpre[64 + lane] = tot0 + ((lane < NBLK - 64) ? (i1 - c1) : 0);
        if (lane == 0) { sK = tot0 + tot1; kg[g] = (u32)(tot0 + tot1); }
    }
    __syncthreads();
    int K = sK;
    if (K == 0) return;
    int Kc = (K < KMAX) ? K : KMAX;

    for (int blk = wv; blk < NBLK; blk += 8) {
        u64 wmask = (u64)rb32[2 * blk] | ((u64)rb32[2 * blk + 1] << 32);
        if ((wmask >> lane) & 1ull) {
            int pos = bpre[blk] + (int)__popcll(wmask & ((1ull << lane) - 1ull));
            if (pos < KMAX) grankS[pos] = (u16)((blk << 6) | lane);
        }
    }
    __syncthreads();

    float4* bg = boxg + g * KMAX;
    float*  ag = areag + g * KMAX;
    u32*    gr = grankg + g * KMAX;
    for (int m = t; m < KMAX; m += 512) {
        if (m < Kc) {
            int r = grankS[m];
            float4 bb = boxr[r];
            bg[m] = bb;
            ag[m] = (bb.z - bb.x + 1.0f) * (bb.w - bb.y + 1.0f);
            gr[m] = (u32)r;
        } else {
            bg[m] = make_float4(-3e30f, -3e30f, -3e30f, -3e30f);
            ag[m] = 3e38f;
        }
    }
}

/* 5: register-resident 64x64 IoU tiles, one 1-wave block per (group, tile). */
__global__ __launch_bounds__(64) void mask_kernel(const u32* __restrict__ kg,
                                                  const float4* __restrict__ boxg,
                                                  const float* __restrict__ areag,
                                                  u64* __restrict__ maskg) {
    int g = blockIdx.y;
    u32 K = kg[g];
    if (K == 0u) return;
    int Kc = (K < (u32)KMAX) ? (int)K : KMAX;
    int W = (Kc + 63) >> 6;
    int u = blockIdx.x;
    int c = u / MAXW, rbk = u % MAXW;
    if (c >= W || rbk >= W) return;
    int lane = threadIdx.x;
    int r = rbk * 64 + lane;
    u64* mg = maskg + (size_t)g * (KMAX * MSTRIDE);
    if (rbk > c) { mg[r * MSTRIDE + c] = 0ull; return; }
    int j0 = c << 6;
    const float4* bg = boxg + g * KMAX;
    const float*  ag = areag + g * KMAX;
    float4 rb = bg[r];
    float  ra = ag[r];
    float4 cb = bg[j0 + lane];
    float  ca = ag[j0 + lane];
    u64 word = 0ull;
    #pragma unroll 8
    for (int q = 0; q < 64; ++q) {
        float cbx = __shfl(cb.x, q);
        float cby = __shfl(cb.y, q);
        float cbz = __shfl(cb.z, q);
        float cbw = __shfl(cb.w, q);
        float cav = __shfl(ca, q);
        float ih = fminf(rb.z, cbz) - fmaxf(rb.x, cbx) + 1.0f;
        float iw = fminf(rb.w, cbw) - fmaxf(rb.y, cby) + 1.0f;
        ih = fmaxf(ih, 0.0f); iw = fmaxf(iw, 0.0f);
        /* iou>=0.5 <=> 3*inter >= ai+aj */
        bool o = (3.0f * ih * iw >= ra + cav) && ((j0 + q) > r);
        if (o) word |= (1ull << q);
    }
    mg[r * MSTRIDE + c] = word;
}

/* 6: per-group serial greedy. Stage mask L2->LDS coalesced, then chunk-8 scan. */
__global__ __launch_bounds__(512) void greedy_kernel(const u32* __restrict__ kg,
                                                     const u32* __restrict__ grankg,
                                                     const u64* __restrict__ maskg,
                                                     float* __restrict__ out) {
    __shared__ u64 maskm[KMAX * MSTRIDE + 64];   /* 56.8 KB */
    __shared__ u16 grank[KMAX];
    int g = blockIdx.x, t = threadIdx.x, lane = t & 63;
    u32 K = kg[g];
    if (K == 0u) return;
    int Kc = (K < (u32)KMAX) ? (int)K : KMAX;
    int W = (Kc + 63) >> 6;
    const u64* mg = maskg + (size_t)g * (KMAX * MSTRIDE);
    int nw = Kc * MSTRIDE;
    for (int m = t; m < nw; m += 512) maskm[m] = mg[m];
    for (int m = nw + t; m < nw + 64; m += 512) maskm[m] = 0ull;
    for (int m = t; m < Kc; m += 512) grank[m] = (u16)grankg[g * KMAX + m];
    __syncthreads();

    if (t >= 64) return;
    u64 remv = 0ull;
    for (int w = 0; w < W; ++w) {
        int r0 = w << 6;
        int rend = Kc - r0; if (rend > 64) rend = 64;
        u64 curw = __shfl(remv, w);
        u64 kb = 0ull;
        for (int b0 = 0; b0 < rend; b0 += 8) {
            int n = rend - b0; if (n > 8) n = 8;
            u64 mrow[8], dg[8];
            #pragma unroll
            for (int j = 0; j < 8; ++j) {
                int rr = r0 + b0 + ((j < n) ? j : 0);
                mrow[j] = maskm[rr * MSTRIDE + lane];   /* +64 pad covers overrun */
                dg[j]   = maskm[rr * MSTRIDE + w];      /* uniform: broadcast */
            }
            #pragma unroll
            for (int j = 0; j < 8; ++j) {
                if (j < n) {
                    int b = b0 + j;
                    u64 km = ((curw >> b) & 1ull) ? 0ull : ~0ull;
                    curw |= dg[j] & km;
                    remv |= mrow[j] & km;
                    kb |= km & (1ull << b);
                }
            }
        }
        if (lane < rend)
            out[(int)grank[r0 + lane] * 6 + 5] = ((kb >> lane) & 1ull) ? 1.0f : 0.0f;
    }
}

extern "C" void kernel_launch(void* const* d_in, const int* in_sizes, int n_in,
                              void* d_out, int out_size, void* d_ws, size_t ws_size,
                              hipStream_t stream) {
    const float*  probs    = (const float*)d_in[0];
    const float4* deltas4  = (const float4*)d_in[1];
    const float4* anchors4 = (const float4*)d_in[2];
    int n_prop = in_sizes[1] / 4;   /* 522240 */
    int n_anch = in_sizes[2] / 4;   /* 65280  */

    char* ws = (char*)d_ws;
    u32* ctr      = (u32*)(ws + CTR_OFF);
    u32* fineh    = (u32*)(ws + FINEH_OFF);
    u32* bcnt     = (u32*)(ws + BCNT_OFF);
    u32* gbits    = (u32*)(ws + GBITS_OFF);
    u64* cand     = (u64*)(ws + CAND_OFF);
    float4* boxr  = (float4*)(ws + BOXR_OFF);
    u32* kg       = (u32*)(ws + KG_OFF);
    u32* grankg   = (u32*)(ws + GRANKG_OFF);
    float4* boxg  = (float4*)(ws + BOXG_OFF);
    float* areag  = (float*)(ws + AREAG_OFF);
    u64* maskg    = (u64*)(ws + MASKG_OFF);
    u32* base     = (u32*)(ws + BASE_OFF);
    float* out    = (float*)d_out;

    hipMemsetAsync(ws, 0, ZERO_LEN, stream);
    histpivot_kernel<<<NHB, 1024, 0, stream>>>((const float4*)probs, fineh,
                                               ctr, base, n_prop);
    scatter_kernel<<<256, 256, 0, stream>>>((const float4*)probs, ctr, base, bcnt,
                                            cand, n_prop);
    rankdecode_kernel<<<CANDMAX / 256, 256, 0, stream>>>(cand, ctr, base, bcnt,
                                                         deltas4, anchors4,
                                                         boxr, gbits, out, n_anch);
    prep_kernel<<<NGRP, 512, 0, stream>>>(gbits, boxr, kg, grankg, boxg, areag);
    mask_kernel<<<dim3(MTILE, NGRP), 64, 0, stream>>>(kg, boxg, areag, maskg);
    greedy_kernel<<<NGRP, 512, 0, stream>>>(kg, grankg, maskg, out);
}

// Round 15
// 137.650 us; speedup vs baseline: 1.0531x; 1.0178x over previous
//
#include <hip/hip_runtime.h>
#include <math.h>

typedef unsigned int u32;
typedef unsigned short u16;
typedef unsigned long long u64;

#define PRE_NMS 6000
#define NBLK    94          /* ceil(6000/64) rank-bitmap words */
#define KMAX    640         /* group capacity (E[K]~375) */
#define MSTRIDE 11          /* mask row stride, > KMAX/64 */
#define MAXW    10          /* max 64-blocks per group */
#define MTILE   (MAXW * MAXW)
#define FINEB   8192        /* [0.5,1) buckets, 2^10 ulp each */
#define LOWB    8064        /* [0,0.5) buckets, bits>>17 */
#define NHB     64          /* hist blocks */
#define CANDMAX 16384
#define NGRP    24
#define FLOOR_BITS 0x3F000000u   /* 0.5f */

/* ws byte offsets ([CTR|FINEH|BCNT|GBITS] contiguous -> one zero kernel) */
#define CTR_OFF    0          /* 64 u32 -> 256 ([0]=M [1]=pivot) */
#define FINEH_OFF  256        /* 8192 u32 -> 33024 */
#define BCNT_OFF   33024      /* 16384 u32 -> 98560 */
#define GBITS_OFF  98560      /* 24*192 u32 -> 116992 */
#define ZERO_U32   29248      /* (116992)/4 u32 words zeroed from 0 */
#define CAND_OFF   116992     /* 16384 u64 -> 248064 */
#define BOXR_OFF   248064     /* 6016 float4 -> 344320 */
#define KG_OFF     344320     /* 64 u32 -> 344576 */
#define GRANKG_OFF 344576     /* 24*640 u32 -> 406016 */
#define BOXG_OFF   406016     /* 24*640 float4 -> 651776 */
#define AREAG_OFF  651776     /* 24*640 f32 -> 713216 */
#define MASKG_OFF  713216     /* 24*640*11 u64 -> 2064896 */
#define BASE_OFF   2064896    /* 16384 u32 -> 2130432 */

/* bucket index in [0,16384): fine fb in [0,8192), low 8192+lb */
__device__ __forceinline__ u32 bucket_of(u32 bits) {
    if (bits >= FLOOR_BITS) {
        u32 fb = (bits - FLOOR_BITS) >> 10; if (fb > FINEB - 1) fb = FINEB - 1;
        return fb;
    }
    return 8192u + (bits >> 17);
}

/* 0: zero working state (replaces hipMemsetAsync — no runtime API in the
   launch path beyond kernel launches, in case capture rules tightened). */
__global__ __launch_bounds__(256) void zero_kernel(u32* __restrict__ p) {
    int i = blockIdx.x * 256 + threadIdx.x;
    int stride = gridDim.x * 256;
    for (; i < ZERO_U32; i += stride) p[i] = 0u;
}

/* 1: fine-range-only histogram. Values < 0.5 are NOT histogrammed (they
   can't matter: fineTotal >= 6000 in practice; pivot_kernel's fallback
   covers the theoretical case). Sparse atomic merge into global fineh.
   No cross-workgroup sync (R8-R10 "ticket" quarantined). */
__global__ __launch_bounds__(1024) void hist_kernel(const float4* __restrict__ probs4,
                                                    u32* __restrict__ fineh,
                                                    int n_prop) {
    __shared__ u32 hf[FINEB];      /* 32 KB */
    int t = threadIdx.x;
    for (int i = t; i < FINEB; i += 1024) hf[i] = 0u;
    __syncthreads();
    int nq = n_prop >> 2;
    int idx = blockIdx.x * 1024 + t;
    int stride = gridDim.x * 1024;
    for (int q = idx; q < nq; q += stride) {
        float4 a = probs4[3 * q + 0];
        float4 b = probs4[3 * q + 1];
        float4 c = probs4[3 * q + 2];
        float vs[8] = {a.y, a.z, b.x, b.y, b.w, c.x, c.z, c.w};
        #pragma unroll
        for (int e = 0; e < 8; ++e) {
            u32 bits = __float_as_uint(vs[e]);
            if (bits >= FLOOR_BITS) {
                u32 fb = (bits - FLOOR_BITS) >> 10; if (fb >= FINEB) fb = FINEB - 1;
                atomicAdd(&hf[fb], 1u);
            }
        }
    }
    __syncthreads();
    for (int b = t; b < FINEB; b += 1024) {
        u32 v = hf[b];
        if (v) atomicAdd(&fineh[b], v);
    }
}

/* 2: single-block pivot: read pre-reduced fineh (32 KB), suffix-scan from
   top -> exact pivot + per-bucket base ranks. If fineTotal < 6000 (never
   expected) this block re-reads probs and histograms the low range itself. */
__global__ __launch_bounds__(1024) void pivot_kernel(const float4* __restrict__ probs4,
                                                     const u32* __restrict__ fineh,
                                                     u32* __restrict__ ctr,
                                                     u32* __restrict__ base,
                                                     int n_prop) {
    __shared__ u32 fh[FINEB];      /* 32 KB */
    __shared__ u32 sd[1024];       /* 4 KB  */
    __shared__ u32 hlow[LOWB];     /* 31.5 KB (fallback only) */
    int t = threadIdx.x;
    for (int b = t; b < FINEB; b += 1024) fh[b] = fineh[b];
    __syncthreads();
    int hi = FINEB - 1 - 8 * t;
    u32 L = 0;
    #pragma unroll
    for (int e = 0; e < 8; ++e) L += fh[hi - e];
    sd[t] = L;
    __syncthreads();
    for (int off = 1; off < 1024; off <<= 1) {
        u32 x = (t >= off) ? sd[t - off] : 0u;
        __syncthreads();
        sd[t] += x;
        __syncthreads();
    }
    u32 incl = sd[t], excl = incl - L;
    u32 fineTotal = sd[1023];
    {
        u32 run = excl;
        #pragma unroll
        for (int e = 0; e < 8; ++e) {
            int fb = hi - e;
            base[fb] = run;
            u32 c = fh[fb];
            if (run < (u32)PRE_NMS && run + c >= (u32)PRE_NMS) {
                ctr[1] = FLOOR_BITS + ((u32)fb << 10);
                u32 m = run + c; if (m > (u32)CANDMAX) m = (u32)CANDMAX;
                ctr[0] = m;
            }
            run += c;
        }
    }
    if (fineTotal >= (u32)PRE_NMS) return;

    /* fallback (never expected): re-read probs, histogram low range here. */
    u32 rem = (u32)PRE_NMS - fineTotal;
    int nq = n_prop >> 2;
    __syncthreads();
    for (int i = t; i < LOWB; i += 1024) hlow[i] = 0u;
    __syncthreads();
    for (int q = t; q < nq; q += 1024) {
        float4 a = probs4[3 * q + 0];
        float4 b = probs4[3 * q + 1];
        float4 c = probs4[3 * q + 2];
        float vs[8] = {a.y, a.z, b.x, b.y, b.w, c.x, c.z, c.w};
        #pragma unroll
        for (int e = 0; e < 8; ++e) {
            u32 bits = __float_as_uint(vs[e]);
            if (bits < FLOOR_BITS) atomicAdd(&hlow[bits >> 17], 1u);
        }
    }
    __syncthreads();
    for (int b = t; b < FINEB; b += 1024) fh[b] = (b < LOWB) ? hlow[b] : 0u;
    __syncthreads();
    L = 0;
    #pragma unroll
    for (int e = 0; e < 8; ++e) L += fh[hi - e];
    sd[t] = L;
    __syncthreads();
    for (int off = 1; off < 1024; off <<= 1) {
        u32 x = (t >= off) ? sd[t - off] : 0u;
        __syncthreads();
        sd[t] += x;
        __syncthreads();
    }
    incl = sd[t]; excl = incl - L;
    {
        u32 run = excl;
        #pragma unroll
        for (int e = 0; e < 8; ++e) {
            int lb = hi - e;
            base[8192 + lb] = fineTotal + run;
            u32 c = fh[lb];
            if (run < rem && run + c >= rem) {
                ctr[1] = ((u32)lb) << 17;
                u32 m = fineTotal + run + c; if (m > (u32)CANDMAX) m = (u32)CANDMAX;
                ctr[0] = m;
            }
            run += c;
        }
    }
}

/* 3: scatter-compact: candidate -> its bucket's contiguous slot range. */
__global__ __launch_bounds__(256) void scatter_kernel(const float4* __restrict__ probs4,
                                                      const u32* __restrict__ ctr,
                                                      const u32* __restrict__ base,
                                                      u32* __restrict__ bcnt,
                                                      u64* __restrict__ cand,
                                                      int n_prop) {
    u32 pivot = ctr[1];
    int nq = n_prop >> 2;
    int idx = blockIdx.x * 256 + threadIdx.x;
    int stride = gridDim.x * 256;
    for (int q = idx; q < nq; q += stride) {
        float4 a = probs4[3 * q + 0];
        float4 b = probs4[3 * q + 1];
        float4 c = probs4[3 * q + 2];
        float vs[8] = {a.y, a.z, b.x, b.y, b.w, c.x, c.z, c.w};
        #pragma unroll
        for (int e = 0; e < 8; ++e) {
            u32 bits = __float_as_uint(vs[e]);
            if (bits >= pivot) {
                u32 bk = bucket_of(bits);
                u32 off = atomicAdd(&bcnt[bk], 1u);
                u32 slot = base[bk] + off;
                u32 i = (u32)(8 * q + e);
                if (slot < (u32)CANDMAX) cand[slot] = ((u64)bits << 32) | (u64)(~i);
            }
        }
    }
}

/* 4: local rank (bucket base + count-greater among tiny bucket group) + decode. */
__global__ __launch_bounds__(256) void rankdecode_kernel(const u64* __restrict__ cand,
                                                         const u32* __restrict__ ctr,
                                                         const u32* __restrict__ base,
                                                         const u32* __restrict__ bcnt,
                                                         const float4* __restrict__ deltas4,
                                                         const float4* __restrict__ anchors4,
                                                         float4* __restrict__ boxr,
                                                         u32* __restrict__ gbits,
                                                         float* __restrict__ out,
                                                         int n_anch) {
    u32 M = ctr[0]; if (M > (u32)CANDMAX) M = (u32)CANDMAX;
    u32 i = blockIdx.x * 256 + threadIdx.x;
    if (i >= M) return;
    u64 key = cand[i];
    u32 bits = (u32)(key >> 32);
    u32 bk = bucket_of(bits);
    u32 b0 = base[bk];
    u32 n = bcnt[bk];
    u32 r = b0;
    if (n > 1) {
        u32 end = b0 + n; if (end > M) end = M;
        u32 cnt = 0;
        for (u32 j = b0; j < end; ++j) cnt += (cand[j] > key) ? 1u : 0u;
        r = b0 + cnt;
    }
    if (r >= (u32)PRE_NMS) return;
    u32 flat = ~((u32)key);
    int p = (int)(flat >> 1);
    int cls = (int)(flat & 1u) + 1;
    int b = p / n_anch;
    int g = b * 3 + cls;
    int aidx = p - b * n_anch;
    float score = __uint_as_float(bits);
    float4 a = anchors4[aidx];
    float4 d = deltas4[p];
    float d0 = d.x * 0.1f, d1 = d.y * 0.1f, d2 = d.z * 0.2f, d3 = d.w * 0.2f;
    float y1 = a.x * (1.0f / 512.0f), x1 = a.y * (1.0f / 512.0f);
    float y2 = a.z * (1.0f / 512.0f), x2 = a.w * (1.0f / 512.0f);
    float h = y2 - y1, w = x2 - x1;
    float cy = y1 + 0.5f * h + d0 * h;
    float cx = x1 + 0.5f * w + d1 * w;
    h = h * expf(d2);
    w = w * expf(d3);
    float ry1 = (cy - 0.5f * h) * 512.0f;
    float rx1 = (cx - 0.5f * w) * 512.0f;
    float ry2 = (cy - 0.5f * h + h) * 512.0f;
    float rx2 = (cx - 0.5f * w + w) * 512.0f;
    ry1 = fminf(fmaxf(ry1, 0.0f), 512.0f);
    rx1 = fminf(fmaxf(rx1, 0.0f), 512.0f);
    ry2 = fminf(fmaxf(ry2, 0.0f), 512.0f);
    rx2 = fminf(fmaxf(rx2, 0.0f), 512.0f);
    out[r * 6 + 0] = ry1;
    out[r * 6 + 1] = rx1;
    out[r * 6 + 2] = ry2;
    out[r * 6 + 3] = rx2;
    out[r * 6 + 4] = score;
    out[r * 6 + 5] = 1.0f;               /* default keep; greedy overwrites */
    out[PRE_NMS * 6 + r] = (float)cls;
    out[PRE_NMS * 7 + r] = (float)b;
    boxr[r] = make_float4(ry1, rx1, ry2, rx2);
    atomicOr(&gbits[g * 192 + (r >> 5)], 1u << (r & 31));
}

/* 5: per-group prep: bitmap prefix -> rank-ordered box table in global
   (sentinel-padded to KMAX), grank table, K. */
__global__ __launch_bounds__(512) void prep_kernel(const u32* __restrict__ gbits,
                                                   const float4* __restrict__ boxr,
                                                   u32* __restrict__ kg,
                                                   u32* __restrict__ grankg,
                                                   float4* __restrict__ boxg,
                                                   float* __restrict__ areag) {
    __shared__ int bpre[96];
    __shared__ u16 grankS[KMAX];
    __shared__ int sK;
    int g = blockIdx.x, t = threadIdx.x, lane = t & 63, wv = t >> 6;
    const u32* rb32 = gbits + g * 192;

    if (t < 64) {
        u64 w0 = (u64)rb32[2 * lane] | ((u64)rb32[2 * lane + 1] << 32);
        u64 w1 = (lane < NBLK - 64)
                 ? ((u64)rb32[128 + 2 * lane] | ((u64)rb32[129 + 2 * lane] << 32)) : 0ull;
        int c0 = (int)__popcll(w0), c1 = (int)__popcll(w1);
        int i0 = c0, i1 = c1;
        #pragma unroll
        for (int off = 1; off < 64; off <<= 1) {
            int a = __shfl_up(i0, off); if (lane >= off) i0 += a;
            int b = __shfl_up(i1, off); if (lane >= off) i1 += b;
        }
        int tot0 = __shfl(i0, 63), tot1 = __shfl(i1, 63);
        bpre[lane] = i0 - c0;
        if (lane < 32) bpre[64 + lane] = tot0 + ((lane < NBLK - 64) ? (i1 - c1) : 0);
        if (lane == 0) { sK = tot0 + tot1; kg[g] = (u32)(tot0 + tot1); }
    }
    __syncthreads();
    int K = sK;
    if (K == 0) return;
    int Kc = (K < KMAX) ? K : KMAX;

    for (int blk = wv; blk < NBLK; blk += 8) {
        u64 wmask = (u64)rb32[2 * blk] | ((u64)rb32[2 * blk + 1] << 32);
        if ((wmask >> lane) & 1ull) {
            int pos = bpre[blk] + (int)__popcll(wmask & ((1ull << lane) - 1ull));
            if (pos < KMAX) grankS[pos] = (u16)((blk << 6) | lane);
        }
    }
    __syncthreads();

    float4* bg = boxg + g * KMAX;
    float*  ag = areag + g * KMAX;
    u32*    gr = grankg + g * KMAX;
    for (int m = t; m < KMAX; m += 512) {
        if (m < Kc) {
            int r = grankS[m];
            float4 bb = boxr[r];
            bg[m] = bb;
            ag[m] = (bb.z - bb.x + 1.0f) * (bb.w - bb.y + 1.0f);
            gr[m] = (u32)r;
        } else {
            bg[m] = make_float4(-3e30f, -3e30f, -3e30f, -3e30f);
            ag[m] = 3e38f;
        }
    }
}

/* 6: register-resident 64x64 IoU tiles, one 1-wave block per (group, tile). */
__global__ __launch_bounds__(64) void mask_kernel(const u32* __restrict__ kg,
                                                  const float4* __restrict__ boxg,
                                                  const float* __restrict__ areag,
                                                  u64* __restrict__ maskg) {
    int g = blockIdx.y;
    u32 K = kg[g];
    if (K == 0u) return;
    int Kc = (K < (u32)KMAX) ? (int)K : KMAX;
    int W = (Kc + 63) >> 6;
    int u = blockIdx.x;
    int c = u / MAXW, rbk = u % MAXW;
    if (c >= W || rbk >= W) return;
    int lane = threadIdx.x;
    int r = rbk * 64 + lane;
    u64* mg = maskg + (size_t)g * (KMAX * MSTRIDE);
    if (rbk > c) { mg[r * MSTRIDE + c] = 0ull; return; }
    int j0 = c << 6;
    const float4* bg = boxg + g * KMAX;
    const float*  ag = areag + g * KMAX;
    float4 rb = bg[r];
    float  ra = ag[r];
    float4 cb = bg[j0 + lane];
    float  ca = ag[j0 + lane];
    u64 word = 0ull;
    #pragma unroll 8
    for (int q = 0; q < 64; ++q) {
        float cbx = __shfl(cb.x, q);
        float cby = __shfl(cb.y, q);
        float cbz = __shfl(cb.z, q);
        float cbw = __shfl(cb.w, q);
        float cav = __shfl(ca, q);
        float ih = fminf(rb.z, cbz) - fmaxf(rb.x, cbx) + 1.0f;
        float iw = fminf(rb.w, cbw) - fmaxf(rb.y, cby) + 1.0f;
        ih = fmaxf(ih, 0.0f); iw = fmaxf(iw, 0.0f);
        /* iou>=0.5 <=> 3*inter >= ai+aj */
        bool o = (3.0f * ih * iw >= ra + cav) && ((j0 + q) > r);
        if (o) word |= (1ull << q);
    }
    mg[r * MSTRIDE + c] = word;
}

/* 7: per-group serial greedy. Stage mask L2->LDS coalesced, then chunk-8 scan. */
__global__ __launch_bounds__(512) void greedy_kernel(const u32* __restrict__ kg,
                                                     const u32* __restrict__ grankg,
                                                     const u64* __restrict__ maskg,
                                                     float* __restrict__ out) {
    __shared__ u64 maskm[KMAX * MSTRIDE + 64];   /* 56.8 KB */
    __shared__ u16 grank[KMAX];
    int g = blockIdx.x, t = threadIdx.x, lane = t & 63;
    u32 K = kg[g];
    if (K == 0u) return;
    int Kc = (K < (u32)KMAX) ? (int)K : KMAX;
    int W = (Kc + 63) >> 6;
    const u64* mg = maskg + (size_t)g * (KMAX * MSTRIDE);
    int nw = Kc * MSTRIDE;
    for (int m = t; m < nw; m += 512) maskm[m] = mg[m];
    for (int m = nw + t; m < nw + 64; m += 512) maskm[m] = 0ull;
    for (int m = t; m < Kc; m += 512) grank[m] = (u16)grankg[g * KMAX + m];
    __syncthreads();

    if (t >= 64) return;
    u64 remv = 0ull;
    for (int w = 0; w < W; ++w) {
        int r0 = w << 6;
        int rend = Kc - r0; if (rend > 64) rend = 64;
        u64 curw = __shfl(remv, w);
        u64 kb = 0ull;
        for (int b0 = 0; b0 < rend; b0 += 8) {
            int n = rend - b0; if (n > 8) n = 8;
            u64 mrow[8], dg[8];
            #pragma unroll
            for (int j = 0; j < 8; ++j) {
                int rr = r0 + b0 + ((j < n) ? j : 0);
                mrow[j] = maskm[rr * MSTRIDE + lane];   /* +64 pad covers overrun */
                dg[j]   = maskm[rr * MSTRIDE + w];      /* uniform: broadcast */
            }
            #pragma unroll
            for (int j = 0; j < 8; ++j) {
                if (j < n) {
                    int b = b0 + j;
                    u64 km = ((curw >> b) & 1ull) ? 0ull : ~0ull;
                    curw |= dg[j] & km;
                    remv |= mrow[j] & km;
                    kb |= km & (1ull << b);
                }
            }
        }
        if (lane < rend)
            out[(int)grank[r0 + lane] * 6 + 5] = ((kb >> lane) & 1ull) ? 1.0f : 0.0f;
    }
}

extern "C" void kernel_launch(void* const* d_in, const int* in_sizes, int n_in,
                              void* d_out, int out_size, void* d_ws, size_t ws_size,
                              hipStream_t stream) {
    const float*  probs    = (const float*)d_in[0];
    const float4* deltas4  = (const float4*)d_in[1];
    const float4* anchors4 = (const float4*)d_in[2];
    int n_prop = in_sizes[1] / 4;   /* 522240 */
    int n_anch = in_sizes[2] / 4;   /* 65280  */

    char* ws = (char*)d_ws;
    u32* ctr      = (u32*)(ws + CTR_OFF);
    u32* fineh    = (u32*)(ws + FINEH_OFF);
    u32* bcnt     = (u32*)(ws + BCNT_OFF);
    u32* gbits    = (u32*)(ws + GBITS_OFF);
    u64* cand     = (u64*)(ws + CAND_OFF);
    float4* boxr  = (float4*)(ws + BOXR_OFF);
    u32* kg       = (u32*)(ws + KG_OFF);
    u32* grankg   = (u32*)(ws + GRANKG_OFF);
    float4* boxg  = (float4*)(ws + BOXG_OFF);
    float* areag  = (float*)(ws + AREAG_OFF);
    u64* maskg    = (u64*)(ws + MASKG_OFF);
    u32* base     = (u32*)(ws + BASE_OFF);
    float* out    = (float*)d_out;

    zero_kernel<<<64, 256, 0, stream>>>((u32*)ws);
    hist_kernel<<<NHB, 1024, 0, stream>>>((const float4*)probs, fineh, n_prop);
    pivot_kernel<<<1, 1024, 0, stream>>>((const float4*)probs, fineh, ctr, base, n_prop);
    scatter_kernel<<<256, 256, 0, stream>>>((const float4*)probs, ctr, base, bcnt,
                                            cand, n_prop);
    rankdecode_kernel<<<CANDMAX / 256, 256, 0, stream>>>(cand, ctr, base, bcnt,
                                                         deltas4, anchors4,
                                                         boxr, gbits, out, n_anch);
    prep_kernel<<<NGRP, 512, 0, stream>>>(gbits, boxr, kg, grankg, boxg, areag);
    mask_kernel<<<dim3(MTILE, NGRP), 64, 0, stream>>>(kg, boxg, areag, maskg);
    greedy_kernel<<<NGRP, 512, 0, stream>>>(kg, grankg, maskg, out);
}

// Round 16
// 137.430 us; speedup vs baseline: 1.0548x; 1.0016x over previous
//
#include <hip/hip_runtime.h>
#include <math.h>

typedef unsigned int u32;
typedef unsigned short u16;
typedef unsigned long long u64;

#define PRE_NMS 6000
#define NBLK    94          /* ceil(6000/64) rank-bitmap words */
#define KMAX    640         /* group capacity (E[K]~375) */
#define MSTRIDE 11          /* mask row stride, > KMAX/64 */
#define MAXW    10          /* max 64-blocks per group */
#define MTILE   (MAXW * MAXW)
#define FINEB   8192        /* [0.5,1) buckets, 2^10 ulp each */
#define LOWB    8064        /* [0,0.5) buckets, bits>>17 */
#define NHB     64          /* hist blocks */
#define CANDMAX 16384
#define NGRP    24
#define FLOOR_BITS 0x3F000000u   /* 0.5f */

/* ws byte offsets ([CTR|FINEH|BCNT|GBITS] contiguous -> one zero kernel) */
#define CTR_OFF    0          /* 64 u32 -> 256 ([0]=M [1]=pivot) */
#define FINEH_OFF  256        /* 8192 u32 -> 33024 */
#define BCNT_OFF   33024      /* 16384 u32 -> 98560 */
#define GBITS_OFF  98560      /* 24*192 u32 -> 116992 */
#define ZERO_U32   29248      /* (116992)/4 u32 words zeroed from 0 */
#define CAND_OFF   116992     /* 16384 u64 -> 248064 */
#define BOXR_OFF   248064     /* 6016 float4 -> 344320 */
#define MASKG_OFF  344320     /* 24*640*11 u64 -> 1696000 */
#define BASE_OFF   1696000    /* 16384 u32 -> 1761536 */

/* bucket index in [0,16384): fine fb in [0,8192), low 8192+lb */
__device__ __forceinline__ u32 bucket_of(u32 bits) {
    if (bits >= FLOOR_BITS) {
        u32 fb = (bits - FLOOR_BITS) >> 10; if (fb > FINEB - 1) fb = FINEB - 1;
        return fb;
    }
    return 8192u + (bits >> 17);
}

/* 0: zero working state (hipMemsetAsync is process-fatal in this harness
   since ~R11 — keep all zeroing in a kernel). */
__global__ __launch_bounds__(256) void zero_kernel(u32* __restrict__ p) {
    int i = blockIdx.x * 256 + threadIdx.x;
    int stride = gridDim.x * 256;
    for (; i < ZERO_U32; i += stride) p[i] = 0u;
}

/* 1: fine-range-only histogram. Values < 0.5 are NOT histogrammed (they
   can't matter: fineTotal >= 6000 in practice; pivot_kernel's fallback
   covers the theoretical case). Sparse atomic merge into global fineh. */
__global__ __launch_bounds__(1024) void hist_kernel(const float4* __restrict__ probs4,
                                                    u32* __restrict__ fineh,
                                                    int n_prop) {
    __shared__ u32 hf[FINEB];      /* 32 KB */
    int t = threadIdx.x;
    for (int i = t; i < FINEB; i += 1024) hf[i] = 0u;
    __syncthreads();
    int nq = n_prop >> 2;
    int idx = blockIdx.x * 1024 + t;
    int stride = gridDim.x * 1024;
    for (int q = idx; q < nq; q += stride) {
        float4 a = probs4[3 * q + 0];
        float4 b = probs4[3 * q + 1];
        float4 c = probs4[3 * q + 2];
        float vs[8] = {a.y, a.z, b.x, b.y, b.w, c.x, c.z, c.w};
        #pragma unroll
        for (int e = 0; e < 8; ++e) {
            u32 bits = __float_as_uint(vs[e]);
            if (bits >= FLOOR_BITS) {
                u32 fb = (bits - FLOOR_BITS) >> 10; if (fb >= FINEB) fb = FINEB - 1;
                atomicAdd(&hf[fb], 1u);
            }
        }
    }
    __syncthreads();
    for (int b = t; b < FINEB; b += 1024) {
        u32 v = hf[b];
        if (v) atomicAdd(&fineh[b], v);
    }
}

/* 2: single-block pivot: read pre-reduced fineh (32 KB), suffix-scan from
   top -> exact pivot + per-bucket base ranks. If fineTotal < 6000 (never
   expected) this block re-reads probs and histograms the low range itself. */
__global__ __launch_bounds__(1024) void pivot_kernel(const float4* __restrict__ probs4,
                                                     const u32* __restrict__ fineh,
                                                     u32* __restrict__ ctr,
                                                     u32* __restrict__ base,
                                                     int n_prop) {
    __shared__ u32 fh[FINEB];      /* 32 KB */
    __shared__ u32 sd[1024];       /* 4 KB  */
    __shared__ u32 hlow[LOWB];     /* 31.5 KB (fallback only) */
    int t = threadIdx.x;
    for (int b = t; b < FINEB; b += 1024) fh[b] = fineh[b];
    __syncthreads();
    int hi = FINEB - 1 - 8 * t;
    u32 L = 0;
    #pragma unroll
    for (int e = 0; e < 8; ++e) L += fh[hi - e];
    sd[t] = L;
    __syncthreads();
    for (int off = 1; off < 1024; off <<= 1) {
        u32 x = (t >= off) ? sd[t - off] : 0u;
        __syncthreads();
        sd[t] += x;
        __syncthreads();
    }
    u32 incl = sd[t], excl = incl - L;
    u32 fineTotal = sd[1023];
    {
        u32 run = excl;
        #pragma unroll
        for (int e = 0; e < 8; ++e) {
            int fb = hi - e;
            base[fb] = run;
            u32 c = fh[fb];
            if (run < (u32)PRE_NMS && run + c >= (u32)PRE_NMS) {
                ctr[1] = FLOOR_BITS + ((u32)fb << 10);
                u32 m = run + c; if (m > (u32)CANDMAX) m = (u32)CANDMAX;
                ctr[0] = m;
            }
            run += c;
        }
    }
    if (fineTotal >= (u32)PRE_NMS) return;

    /* fallback (never expected): re-read probs, histogram low range here. */
    u32 rem = (u32)PRE_NMS - fineTotal;
    int nq = n_prop >> 2;
    __syncthreads();
    for (int i = t; i < LOWB; i += 1024) hlow[i] = 0u;
    __syncthreads();
    for (int q = t; q < nq; q += 1024) {
        float4 a = probs4[3 * q + 0];
        float4 b = probs4[3 * q + 1];
        float4 c = probs4[3 * q + 2];
        float vs[8] = {a.y, a.z, b.x, b.y, b.w, c.x, c.z, c.w};
        #pragma unroll
        for (int e = 0; e < 8; ++e) {
            u32 bits = __float_as_uint(vs[e]);
            if (bits < FLOOR_BITS) atomicAdd(&hlow[bits >> 17], 1u);
        }
    }
    __syncthreads();
    for (int b = t; b < FINEB; b += 1024) fh[b] = (b < LOWB) ? hlow[b] : 0u;
    __syncthreads();
    L = 0;
    #pragma unroll
    for (int e = 0; e < 8; ++e) L += fh[hi - e];
    sd[t] = L;
    __syncthreads();
    for (int off = 1; off < 1024; off <<= 1) {
        u32 x = (t >= off) ? sd[t - off] : 0u;
        __syncthreads();
        sd[t] += x;
        __syncthreads();
    }
    incl = sd[t]; excl = incl - L;
    {
        u32 run = excl;
        #pragma unroll
        for (int e = 0; e < 8; ++e) {
            int lb = hi - e;
            base[8192 + lb] = fineTotal + run;
            u32 c = fh[lb];
            if (run < rem && run + c >= rem) {
                ctr[1] = ((u32)lb) << 17;
                u32 m = fineTotal + run + c; if (m > (u32)CANDMAX) m = (u32)CANDMAX;
                ctr[0] = m;
            }
            run += c;
        }
    }
}

/* 3: scatter-compact: candidate -> its bucket's contiguous slot range. */
__global__ __launch_bounds__(256) void scatter_kernel(const float4* __restrict__ probs4,
                                                      const u32* __restrict__ ctr,
                                                      const u32* __restrict__ base,
                                                      u32* __restrict__ bcnt,
                                                      u64* __restrict__ cand,
                                                      int n_prop) {
    u32 pivot = ctr[1];
    int nq = n_prop >> 2;
    int idx = blockIdx.x * 256 + threadIdx.x;
    int stride = gridDim.x * 256;
    for (int q = idx; q < nq; q += stride) {
        float4 a = probs4[3 * q + 0];
        float4 b = probs4[3 * q + 1];
        float4 c = probs4[3 * q + 2];
        float vs[8] = {a.y, a.z, b.x, b.y, b.w, c.x, c.z, c.w};
        #pragma unroll
        for (int e = 0; e < 8; ++e) {
            u32 bits = __float_as_uint(vs[e]);
            if (bits >= pivot) {
                u32 bk = bucket_of(bits);
                u32 off = atomicAdd(&bcnt[bk], 1u);
                u32 slot = base[bk] + off;
                u32 i = (u32)(8 * q + e);
                if (slot < (u32)CANDMAX) cand[slot] = ((u64)bits << 32) | (u64)(~i);
            }
        }
    }
}

/* 4: local rank (bucket base + count-greater among tiny bucket group) + decode. */
__global__ __launch_bounds__(256) void rankdecode_kernel(const u64* __restrict__ cand,
                                                         const u32* __restrict__ ctr,
                                                         const u32* __restrict__ base,
                                                         const u32* __restrict__ bcnt,
                                                         const float4* __restrict__ deltas4,
                                                         const float4* __restrict__ anchors4,
                                                         float4* __restrict__ boxr,
                                                         u32* __restrict__ gbits,
                                                         float* __restrict__ out,
                                                         int n_anch) {
    u32 M = ctr[0]; if (M > (u32)CANDMAX) M = (u32)CANDMAX;
    u32 i = blockIdx.x * 256 + threadIdx.x;
    if (i >= M) return;
    u64 key = cand[i];
    u32 bits = (u32)(key >> 32);
    u32 bk = bucket_of(bits);
    u32 b0 = base[bk];
    u32 n = bcnt[bk];
    u32 r = b0;
    if (n > 1) {
        u32 end = b0 + n; if (end > M) end = M;
        u32 cnt = 0;
        for (u32 j = b0; j < end; ++j) cnt += (cand[j] > key) ? 1u : 0u;
        r = b0 + cnt;
    }
    if (r >= (u32)PRE_NMS) return;
    u32 flat = ~((u32)key);
    int p = (int)(flat >> 1);
    int cls = (int)(flat & 1u) + 1;
    int b = p / n_anch;
    int g = b * 3 + cls;
    int aidx = p - b * n_anch;
    float score = __uint_as_float(bits);
    float4 a = anchors4[aidx];
    float4 d = deltas4[p];
    float d0 = d.x * 0.1f, d1 = d.y * 0.1f, d2 = d.z * 0.2f, d3 = d.w * 0.2f;
    float y1 = a.x * (1.0f / 512.0f), x1 = a.y * (1.0f / 512.0f);
    float y2 = a.z * (1.0f / 512.0f), x2 = a.w * (1.0f / 512.0f);
    float h = y2 - y1, w = x2 - x1;
    float cy = y1 + 0.5f * h + d0 * h;
    float cx = x1 + 0.5f * w + d1 * w;
    h = h * expf(d2);
    w = w * expf(d3);
    float ry1 = (cy - 0.5f * h) * 512.0f;
    float rx1 = (cx - 0.5f * w) * 512.0f;
    float ry2 = (cy - 0.5f * h + h) * 512.0f;
    float rx2 = (cx - 0.5f * w + w) * 512.0f;
    ry1 = fminf(fmaxf(ry1, 0.0f), 512.0f);
    rx1 = fminf(fmaxf(rx1, 0.0f), 512.0f);
    ry2 = fminf(fmaxf(ry2, 0.0f), 512.0f);
    rx2 = fminf(fmaxf(rx2, 0.0f), 512.0f);
    out[r * 6 + 0] = ry1;
    out[r * 6 + 1] = rx1;
    out[r * 6 + 2] = ry2;
    out[r * 6 + 3] = rx2;
    out[r * 6 + 4] = score;
    out[r * 6 + 5] = 1.0f;               /* default keep; greedy overwrites */
    out[PRE_NMS * 6 + r] = (float)cls;
    out[PRE_NMS * 7 + r] = (float)b;
    boxr[r] = make_float4(ry1, rx1, ry2, rx2);
    atomicOr(&gbits[g * 192 + (r >> 5)], 1u << (r & 31));
}

/* 5: self-ranking register IoU tiles. One 1-wave block per (tile, group).
   The block computes the bitmap prefix itself (no prep kernel), enumerates
   only the two 64-rank windows it needs, fetches boxes from boxr. */
__global__ __launch_bounds__(64) void mask_kernel(const u32* __restrict__ gbits,
                                                  const float4* __restrict__ boxr,
                                                  u64* __restrict__ maskg) {
    __shared__ int bpre[96];
    __shared__ u16 rowRank[64];
    __shared__ u16 colRank[64];
    int g = blockIdx.y;
    int lane = threadIdx.x;
    const u32* rb32 = gbits + g * 192;

    /* A2 prefix over 94 bitmap words (single wave) */
    u64 w0 = (u64)rb32[2 * lane] | ((u64)rb32[2 * lane + 1] << 32);
    u64 w1 = (lane < NBLK - 64)
             ? ((u64)rb32[128 + 2 * lane] | ((u64)rb32[129 + 2 * lane] << 32)) : 0ull;
    int c0 = (int)__popcll(w0), c1 = (int)__popcll(w1);
    int i0 = c0, i1 = c1;
    #pragma unroll
    for (int off = 1; off < 64; off <<= 1) {
        int a = __shfl_up(i0, off); if (lane >= off) i0 += a;
        int b = __shfl_up(i1, off); if (lane >= off) i1 += b;
    }
    int tot0 = __shfl(i0, 63), tot1 = __shfl(i1, 63);
    bpre[lane] = i0 - c0;
    if (lane < 32) bpre[64 + lane] = tot0 + ((lane < NBLK - 64) ? (i1 - c1) : 0);
    int K = tot0 + tot1;
    if (K == 0) return;
    int Kc = (K < KMAX) ? K : KMAX;
    int W = (Kc + 63) >> 6;
    int u = blockIdx.x;
    int c = u / MAXW, rbk = u % MAXW;
    if (c >= W || rbk >= W) return;
    u64* mg = maskg + (size_t)g * (KMAX * MSTRIDE);
    int r = rbk * 64 + lane;
    if (rbk > c) { mg[r * MSTRIDE + c] = 0ull; return; }
    int j0 = c << 6;
    int rowS = rbk << 6;
    __syncthreads();

    /* enumerate set bits of my 1-2 words that land in either rank window */
    {
        int rE = rowS + 64, cE = j0 + 64;
        int blk = lane;
        u64 wm = w0;
        int bb = bpre[blk];
        int pc = c0;
        if (!((bb >= rE || bb + pc <= rowS) && (bb >= cE || bb + pc <= j0))) {
            int pos = bb;
            while (wm) {
                int bit = __ffsll((long long)wm) - 1;
                wm &= wm - 1ull;
                int rr = pos - rowS;
                if (rr >= 0 && rr < 64) rowRank[rr] = (u16)((blk << 6) | bit);
                int cc = pos - j0;
                if (cc >= 0 && cc < 64) colRank[cc] = (u16)((blk << 6) | bit);
                ++pos;
                if (pos >= cE && pos >= rE) break;
            }
        }
        if (lane < NBLK - 64) {
            blk = 64 + lane;
            wm = w1;
            bb = bpre[blk];
            pc = c1;
            if (!((bb >= rE || bb + pc <= rowS) && (bb >= cE || bb + pc <= j0))) {
                int pos = bb;
                while (wm) {
                    int bit = __ffsll((long long)wm) - 1;
                    wm &= wm - 1ull;
                    int rr = pos - rowS;
                    if (rr >= 0 && rr < 64) rowRank[rr] = (u16)((blk << 6) | bit);
                    int cc = pos - j0;
                    if (cc >= 0 && cc < 64) colRank[cc] = (u16)((blk << 6) | bit);
                    ++pos;
                    if (pos >= cE && pos >= rE) break;
                }
            }
        }
    }
    __syncthreads();

    /* load boxes (sentinels beyond Kc) */
    float4 rb, cb;
    float ra, ca;
    if (r < Kc) {
        rb = boxr[rowRank[lane]];
        ra = (rb.z - rb.x + 1.0f) * (rb.w - rb.y + 1.0f);
    } else {
        rb = make_float4(-3e30f, -3e30f, -3e30f, -3e30f);
        ra = 3e38f;
    }
    if (j0 + lane < Kc) {
        cb = boxr[colRank[lane]];
        ca = (cb.z - cb.x + 1.0f) * (cb.w - cb.y + 1.0f);
    } else {
        cb = make_float4(-3e30f, -3e30f, -3e30f, -3e30f);
        ca = 3e38f;
    }
    u64 word = 0ull;
    #pragma unroll 8
    for (int q = 0; q < 64; ++q) {
        float cbx = __shfl(cb.x, q);
        float cby = __shfl(cb.y, q);
        float cbz = __shfl(cb.z, q);
        float cbw = __shfl(cb.w, q);
        float cav = __shfl(ca, q);
        float ih = fminf(rb.z, cbz) - fmaxf(rb.x, cbx) + 1.0f;
        float iw = fminf(rb.w, cbw) - fmaxf(rb.y, cby) + 1.0f;
        ih = fmaxf(ih, 0.0f); iw = fmaxf(iw, 0.0f);
        /* iou>=0.5 <=> 3*inter >= ai+aj */
        bool o = (3.0f * ih * iw >= ra + cav) && ((j0 + q) > r);
        if (o) word |= (1ull << q);
    }
    mg[r * MSTRIDE + c] = word;
}

/* 6: self-ranking per-group serial greedy (A2+A3 inlined; no prep kernel). */
__global__ __launch_bounds__(512) void greedy_kernel(const u32* __restrict__ gbits,
                                                     const u64* __restrict__ maskg,
                                                     float* __restrict__ out) {
    __shared__ u64 maskm[KMAX * MSTRIDE + 64];   /* 56.8 KB */
    __shared__ u16 grank[KMAX];
    __shared__ int bpre[96];
    __shared__ int sK;
    int g = blockIdx.x, t = threadIdx.x, lane = t & 63, wv = t >> 6;
    const u32* rb32 = gbits + g * 192;

    if (t < 64) {
        u64 w0 = (u64)rb32[2 * lane] | ((u64)rb32[2 * lane + 1] << 32);
        u64 w1 = (lane < NBLK - 64)
                 ? ((u64)rb32[128 + 2 * lane] | ((u64)rb32[129 + 2 * lane] << 32)) : 0ull;
        int c0 = (int)__popcll(w0), c1 = (int)__popcll(w1);
        int i0 = c0, i1 = c1;
        #pragma unroll
        for (int off = 1; off < 64; off <<= 1) {
            int a = __shfl_up(i0, off); if (lane >= off) i0 += a;
            int b = __shfl_up(i1, off); if (lane >= off) i1 += b;
        }
        int tot0 = __shfl(i0, 63), tot1 = __shfl(i1, 63);
        bpre[lane] = i0 - c0;
        if (lane < 32) bpre[64 + lane] = tot0 + ((lane < NBLK - 64) ? (i1 - c1) : 0);
        if (lane == 0) sK = tot0 + tot1;
    }
    __syncthreads();
    int K = sK;
    if (K == 0) return;
    int Kc = (K < KMAX) ? K : KMAX;
    int W = (Kc + 63) >> 6;

    for (int blk = wv; blk < NBLK; blk += 8) {
        u64 wmask = (u64)rb32[2 * blk] | ((u64)rb32[2 * blk + 1] << 32);
        if ((wmask >> lane) & 1ull) {
            int pos = bpre[blk] + (int)__popcll(wmask & ((1ull << lane) - 1ull));
            if (pos < KMAX) grank[pos] = (u16)((blk << 6) | lane);
        }
    }
    const u64* mg = maskg + (size_t)g * (KMAX * MSTRIDE);
    int nw = Kc * MSTRIDE;
    for (int m = t; m < nw; m += 512) maskm[m] = mg[m];
    for (int m = nw + t; m < nw + 64; m += 512) maskm[m] = 0ull;
    __syncthreads();

    if (t >= 64) return;
    u64 remv = 0ull;
    for (int w = 0; w < W; ++w) {
        int r0 = w << 6;
        int rend = Kc - r0; if (rend > 64) rend = 64;
        u64 curw = __shfl(remv, w);
        u64 kb = 0ull;
        for (int b0 = 0; b0 < rend; b0 += 8) {
            int n = rend - b0; if (n > 8) n = 8;
            u64 mrow[8], dg[8];
            #pragma unroll
            for (int j = 0; j < 8; ++j) {
                int rr = r0 + b0 + ((j < n) ? j : 0);
                mrow[j] = maskm[rr * MSTRIDE + lane];   /* +64 pad covers overrun */
                dg[j]   = maskm[rr * MSTRIDE + w];      /* uniform: broadcast */
            }
            #pragma unroll
            for (int j = 0; j < 8; ++j) {
                if (j < n) {
                    int b = b0 + j;
                    u64 km = ((curw >> b) & 1ull) ? 0ull : ~0ull;
                    curw |= dg[j] & km;
                    remv |= mrow[j] & km;
                    kb |= km & (1ull << b);
                }
            }
        }
        if (lane < rend)
            out[(int)grank[r0 + lane] * 6 + 5] = ((kb >> lane) & 1ull) ? 1.0f : 0.0f;
    }
}

extern "C" void kernel_launch(void* const* d_in, const int* in_sizes, int n_in,
                              void* d_out, int out_size, void* d_ws, size_t ws_size,
                              hipStream_t stream) {
    const float*  probs    = (const float*)d_in[0];
    const float4* deltas4  = (const float4*)d_in[1];
    const float4* anchors4 = (const float4*)d_in[2];
    int n_prop = in_sizes[1] / 4;   /* 522240 */
    int n_anch = in_sizes[2] / 4;   /* 65280  */

    char* ws = (char*)d_ws;
    u32* ctr      = (u32*)(ws + CTR_OFF);
    u32* fineh    = (u32*)(ws + FINEH_OFF);
    u32* bcnt     = (u32*)(ws + BCNT_OFF);
    u32* gbits    = (u32*)(ws + GBITS_OFF);
    u64* cand     = (u64*)(ws + CAND_OFF);
    float4* boxr  = (float4*)(ws + BOXR_OFF);
    u64* maskg    = (u64*)(ws + MASKG_OFF);
    u32* base     = (u32*)(ws + BASE_OFF);
    float* out    = (float*)d_out;

    zero_kernel<<<64, 256, 0, stream>>>((u32*)ws);
    hist_kernel<<<NHB, 1024, 0, stream>>>((const float4*)probs, fineh, n_prop);
    pivot_kernel<<<1, 1024, 0, stream>>>((const float4*)probs, fineh, ctr, base, n_prop);
    scatter_kernel<<<256, 256, 0, stream>>>((const float4*)probs, ctr, base, bcnt,
                                            cand, n_prop);
    rankdecode_kernel<<<CANDMAX / 256, 256, 0, stream>>>(cand, ctr, base, bcnt,
                                                         deltas4, anchors4,
                                                         boxr, gbits, out, n_anch);
    mask_kernel<<<dim3(MTILE, NGRP), 64, 0, stream>>>(gbits, boxr, maskg);
    greedy_kernel<<<NGRP, 512, 0, stream>>>(gbits, maskg, out);
}

// Round 18
// 136.993 us; speedup vs baseline: 1.0581x; 1.0032x over previous
//
#include <hip/hip_runtime.h>
#include <math.h>

typedef unsigned int u32;
typedef unsigned short u16;
typedef unsigned long long u64;

#define PRE_NMS 6000
#define NBLK    94          /* ceil(6000/64) rank-bitmap words */
#define KMAX    640         /* group capacity (E[K]~375) */
#define MSTRIDE 11          /* mask row stride, > KMAX/64 */
#define MAXW    10          /* max 64-blocks per group */
#define MTILE   (MAXW * MAXW)
#define FINEB   8192        /* [0.5,1) buckets, 2^10 ulp each */
#define LOWB    8064        /* [0,0.5) buckets, bits>>17 */
#define NHB     64          /* hist blocks */
#define CANDMAX 16384
#define NGRP    24
#define FLOOR_BITS 0x3F000000u   /* 0.5f */

/* ws byte offsets ([CTR|FINEH|BCNT|GBITS] contiguous -> one zero kernel) */
#define CTR_OFF    0          /* 64 u32 -> 256 ([0]=M [1]=pivot) */
#define FINEH_OFF  256        /* 8192 u32 -> 33024 */
#define BCNT_OFF   33024      /* 16384 u32 -> 98560 */
#define GBITS_OFF  98560      /* 24*192 u32 -> 116992 */
#define ZERO_U32   29248      /* (116992)/4 u32 words zeroed from 0 */
#define CAND_OFF   116992     /* 16384 u64 -> 248064 */
#define BOXR_OFF   248064     /* 6016 float4 -> 344320 */
#define MASKG_OFF  344320     /* 24*640*11 u64 -> 1696000 */
#define BASE_OFF   1696000    /* 16384 u32 -> 1761536 */

/* bucket index in [0,16384): fine fb in [0,8192), low 8192+lb */
__device__ __forceinline__ u32 bucket_of(u32 bits) {
    if (bits >= FLOOR_BITS) {
        u32 fb = (bits - FLOOR_BITS) >> 10; if (fb > FINEB - 1) fb = FINEB - 1;
        return fb;
    }
    return 8192u + (bits >> 17);
}

/* 0: zero working state (hipMemsetAsync is process-fatal in this harness
   since ~R11 — keep all zeroing in a kernel). Cross-workgroup ticket also
   quarantined (R17): kernel-boundary ordering only. */
__global__ __launch_bounds__(256) void zero_kernel(u32* __restrict__ p) {
    int i = blockIdx.x * 256 + threadIdx.x;
    int stride = gridDim.x * 256;
    for (; i < ZERO_U32; i += stride) p[i] = 0u;
}

/* 1: fine-range-only histogram. Values < 0.5 are NOT histogrammed (they
   can't matter: fineTotal >= 6000 in practice; pivot_kernel's fallback
   covers the theoretical case). Sparse atomic merge into global fineh. */
__global__ __launch_bounds__(1024) void hist_kernel(const float4* __restrict__ probs4,
                                                    u32* __restrict__ fineh,
                                                    int n_prop) {
    __shared__ u32 hf[FINEB];      /* 32 KB */
    int t = threadIdx.x;
    for (int i = t; i < FINEB; i += 1024) hf[i] = 0u;
    __syncthreads();
    int nq = n_prop >> 2;
    int idx = blockIdx.x * 1024 + t;
    int stride = gridDim.x * 1024;
    for (int q = idx; q < nq; q += stride) {
        float4 a = probs4[3 * q + 0];
        float4 b = probs4[3 * q + 1];
        float4 c = probs4[3 * q + 2];
        float vs[8] = {a.y, a.z, b.x, b.y, b.w, c.x, c.z, c.w};
        #pragma unroll
        for (int e = 0; e < 8; ++e) {
            u32 bits = __float_as_uint(vs[e]);
            if (bits >= FLOOR_BITS) {
                u32 fb = (bits - FLOOR_BITS) >> 10; if (fb >= FINEB) fb = FINEB - 1;
                atomicAdd(&hf[fb], 1u);
            }
        }
    }
    __syncthreads();
    for (int b = t; b < FINEB; b += 1024) {
        u32 v = hf[b];
        if (v) atomicAdd(&fineh[b], v);
    }
}

/* 2: single-block pivot: read pre-reduced fineh (32 KB), suffix-scan from
   top -> exact pivot + per-bucket base ranks. If fineTotal < 6000 (never
   expected) this block re-reads probs and histograms the low range itself. */
__global__ __launch_bounds__(1024) void pivot_kernel(const float4* __restrict__ probs4,
                                                     const u32* __restrict__ fineh,
                                                     u32* __restrict__ ctr,
                                                     u32* __restrict__ base,
                                                     int n_prop) {
    __shared__ u32 fh[FINEB];      /* 32 KB */
    __shared__ u32 sd[1024];       /* 4 KB  */
    __shared__ u32 hlow[LOWB];     /* 31.5 KB (fallback only) */
    int t = threadIdx.x;
    for (int b = t; b < FINEB; b += 1024) fh[b] = fineh[b];
    __syncthreads();
    int hi = FINEB - 1 - 8 * t;
    u32 L = 0;
    #pragma unroll
    for (int e = 0; e < 8; ++e) L += fh[hi - e];
    sd[t] = L;
    __syncthreads();
    for (int off = 1; off < 1024; off <<= 1) {
        u32 x = (t >= off) ? sd[t - off] : 0u;
        __syncthreads();
        sd[t] += x;
        __syncthreads();
    }
    u32 incl = sd[t], excl = incl - L;
    u32 fineTotal = sd[1023];
    {
        u32 run = excl;
        #pragma unroll
        for (int e = 0; e < 8; ++e) {
            int fb = hi - e;
            base[fb] = run;
            u32 c = fh[fb];
            if (run < (u32)PRE_NMS && run + c >= (u32)PRE_NMS) {
                ctr[1] = FLOOR_BITS + ((u32)fb << 10);
                u32 m = run + c; if (m > (u32)CANDMAX) m = (u32)CANDMAX;
                ctr[0] = m;
            }
            run += c;
        }
    }
    if (fineTotal >= (u32)PRE_NMS) return;

    /* fallback (never expected): re-read probs, histogram low range here. */
    u32 rem = (u32)PRE_NMS - fineTotal;
    int nq = n_prop >> 2;
    __syncthreads();
    for (int i = t; i < LOWB; i += 1024) hlow[i] = 0u;
    __syncthreads();
    for (int q = t; q < nq; q += 1024) {
        float4 a = probs4[3 * q + 0];
        float4 b = probs4[3 * q + 1];
        float4 c = probs4[3 * q + 2];
        float vs[8] = {a.y, a.z, b.x, b.y, b.w, c.x, c.z, c.w};
        #pragma unroll
        for (int e = 0; e < 8; ++e) {
            u32 bits = __float_as_uint(vs[e]);
            if (bits < FLOOR_BITS) atomicAdd(&hlow[bits >> 17], 1u);
        }
    }
    __syncthreads();
    for (int b = t; b < FINEB; b += 1024) fh[b] = (b < LOWB) ? hlow[b] : 0u;
    __syncthreads();
    L = 0;
    #pragma unroll
    for (int e = 0; e < 8; ++e) L += fh[hi - e];
    sd[t] = L;
    __syncthreads();
    for (int off = 1; off < 1024; off <<= 1) {
        u32 x = (t >= off) ? sd[t - off] : 0u;
        __syncthreads();
        sd[t] += x;
        __syncthreads();
    }
    incl = sd[t]; excl = incl - L;
    {
        u32 run = excl;
        #pragma unroll
        for (int e = 0; e < 8; ++e) {
            int lb = hi - e;
            base[8192 + lb] = fineTotal + run;
            u32 c = fh[lb];
            if (run < rem && run + c >= rem) {
                ctr[1] = ((u32)lb) << 17;
                u32 m = fineTotal + run + c; if (m > (u32)CANDMAX) m = (u32)CANDMAX;
                ctr[0] = m;
            }
            run += c;
        }
    }
}

/* 3: scatter-compact: candidate -> its bucket's contiguous slot range. */
__global__ __launch_bounds__(256) void scatter_kernel(const float4* __restrict__ probs4,
                                                      const u32* __restrict__ ctr,
                                                      const u32* __restrict__ base,
                                                      u32* __restrict__ bcnt,
                                                      u64* __restrict__ cand,
                                                      int n_prop) {
    u32 pivot = ctr[1];
    int nq = n_prop >> 2;
    int idx = blockIdx.x * 256 + threadIdx.x;
    int stride = gridDim.x * 256;
    for (int q = idx; q < nq; q += stride) {
        float4 a = probs4[3 * q + 0];
        float4 b = probs4[3 * q + 1];
        float4 c = probs4[3 * q + 2];
        float vs[8] = {a.y, a.z, b.x, b.y, b.w, c.x, c.z, c.w};
        #pragma unroll
        for (int e = 0; e < 8; ++e) {
            u32 bits = __float_as_uint(vs[e]);
            if (bits >= pivot) {
                u32 bk = bucket_of(bits);
                u32 off = atomicAdd(&bcnt[bk], 1u);
                u32 slot = base[bk] + off;
                u32 i = (u32)(8 * q + e);
                if (slot < (u32)CANDMAX) cand[slot] = ((u64)bits << 32) | (u64)(~i);
            }
        }
    }
}

/* 4: local rank (bucket base + count-greater among tiny bucket group) + decode. */
__global__ __launch_bounds__(256) void rankdecode_kernel(const u64* __restrict__ cand,
                                                         const u32* __restrict__ ctr,
                                                         const u32* __restrict__ base,
                                                         const u32* __restrict__ bcnt,
                                                         const float4* __restrict__ deltas4,
                                                         const float4* __restrict__ anchors4,
                                                         float4* __restrict__ boxr,
                                                         u32* __restrict__ gbits,
                                                         float* __restrict__ out,
                                                         int n_anch) {
    u32 M = ctr[0]; if (M > (u32)CANDMAX) M = (u32)CANDMAX;
    u32 i = blockIdx.x * 256 + threadIdx.x;
    if (i >= M) return;
    u64 key = cand[i];
    u32 bits = (u32)(key >> 32);
    u32 bk = bucket_of(bits);
    u32 b0 = base[bk];
    u32 n = bcnt[bk];
    u32 r = b0;
    if (n > 1) {
        u32 end = b0 + n; if (end > M) end = M;
        u32 cnt = 0;
        for (u32 j = b0; j < end; ++j) cnt += (cand[j] > key) ? 1u : 0u;
        r = b0 + cnt;
    }
    if (r >= (u32)PRE_NMS) return;
    u32 flat = ~((u32)key);
    int p = (int)(flat >> 1);
    int cls = (int)(flat & 1u) + 1;
    int b = p / n_anch;
    int g = b * 3 + cls;
    int aidx = p - b * n_anch;
    float score = __uint_as_float(bits);
    float4 a = anchors4[aidx];
    float4 d = deltas4[p];
    float d0 = d.x * 0.1f, d1 = d.y * 0.1f, d2 = d.z * 0.2f, d3 = d.w * 0.2f;
    float y1 = a.x * (1.0f / 512.0f), x1 = a.y * (1.0f / 512.0f);
    float y2 = a.z * (1.0f / 512.0f), x2 = a.w * (1.0f / 512.0f);
    float h = y2 - y1, w = x2 - x1;
    float cy = y1 + 0.5f * h + d0 * h;
    float cx = x1 + 0.5f * w + d1 * w;
    h = h * expf(d2);
    w = w * expf(d3);
    float ry1 = (cy - 0.5f * h) * 512.0f;
    float rx1 = (cx - 0.5f * w) * 512.0f;
    float ry2 = (cy - 0.5f * h + h) * 512.0f;
    float rx2 = (cx - 0.5f * w + w) * 512.0f;
    ry1 = fminf(fmaxf(ry1, 0.0f), 512.0f);
    rx1 = fminf(fmaxf(rx1, 0.0f), 512.0f);
    ry2 = fminf(fmaxf(ry2, 0.0f), 512.0f);
    rx2 = fminf(fmaxf(rx2, 0.0f), 512.0f);
    out[r * 6 + 0] = ry1;
    out[r * 6 + 1] = rx1;
    out[r * 6 + 2] = ry2;
    out[r * 6 + 3] = rx2;
    out[r * 6 + 4] = score;
    out[r * 6 + 5] = 1.0f;               /* default keep; greedy overwrites */
    out[PRE_NMS * 6 + r] = (float)cls;
    out[PRE_NMS * 7 + r] = (float)b;
    boxr[r] = make_float4(ry1, rx1, ry2, rx2);
    atomicOr(&gbits[g * 192 + (r >> 5)], 1u << (r & 31));
}

/* 5: self-ranking register IoU tiles. One 1-wave block per (tile, group).
   The block computes the bitmap prefix itself (no prep kernel), enumerates
   only the two 64-rank windows it needs, fetches boxes from boxr. */
__global__ __launch_bounds__(64) void mask_kernel(const u32* __restrict__ gbits,
                                                  const float4* __restrict__ boxr,
                                                  u64* __restrict__ maskg) {
    __shared__ int bpre[96];
    __shared__ u16 rowRank[64];
    __shared__ u16 colRank[64];
    int g = blockIdx.y;
    int lane = threadIdx.x;
    const u32* rb32 = gbits + g * 192;

    /* A2 prefix over 94 bitmap words (single wave) */
    u64 w0 = (u64)rb32[2 * lane] | ((u64)rb32[2 * lane + 1] << 32);
    u64 w1 = (lane < NBLK - 64)
             ? ((u64)rb32[128 + 2 * lane] | ((u64)rb32[129 + 2 * lane] << 32)) : 0ull;
    int c0 = (int)__popcll(w0), c1 = (int)__popcll(w1);
    int i0 = c0, i1 = c1;
    #pragma unroll
    for (int off = 1; off < 64; off <<= 1) {
        int a = __shfl_up(i0, off); if (lane >= off) i0 += a;
        int b = __shfl_up(i1, off); if (lane >= off) i1 += b;
    }
    int tot0 = __shfl(i0, 63), tot1 = __shfl(i1, 63);
    bpre[lane] = i0 - c0;
    if (lane < 32) bpre[64 + lane] = tot0 + ((lane < NBLK - 64) ? (i1 - c1) : 0);
    int K = tot0 + tot1;
    if (K == 0) return;
    int Kc = (K < KMAX) ? K : KMAX;
    int W = (Kc + 63) >> 6;
    int u = blockIdx.x;
    int c = u / MAXW, rbk = u % MAXW;
    if (c >= W || rbk >= W) return;
    u64* mg = maskg + (size_t)g * (KMAX * MSTRIDE);
    int r = rbk * 64 + lane;
    if (rbk > c) { mg[r * MSTRIDE + c] = 0ull; return; }
    int j0 = c << 6;
    int rowS = rbk << 6;
    __syncthreads();

    /* enumerate set bits of my 1-2 words that land in either rank window */
    {
        int rE = rowS + 64, cE = j0 + 64;
        int blk = lane;
        u64 wm = w0;
        int bb = bpre[blk];
        int pc = c0;
        if (!((bb >= rE || bb + pc <= rowS) && (bb >= cE || bb + pc <= j0))) {
            int pos = bb;
            while (wm) {
                int bit = __ffsll((long long)wm) - 1;
                wm &= wm - 1ull;
                int rr = pos - rowS;
                if (rr >= 0 && rr < 64) rowRank[rr] = (u16)((blk << 6) | bit);
                int cc = pos - j0;
                if (cc >= 0 && cc < 64) colRank[cc] = (u16)((blk << 6) | bit);
                ++pos;
                if (pos >= cE && pos >= rE) break;
            }
        }
        if (lane < NBLK - 64) {
            blk = 64 + lane;
            wm = w1;
            bb = bpre[blk];
            pc = c1;
            if (!((bb >= rE || bb + pc <= rowS) && (bb >= cE || bb + pc <= j0))) {
                int pos = bb;
                while (wm) {
                    int bit = __ffsll((long long)wm) - 1;
                    wm &= wm - 1ull;
                    int rr = pos - rowS;
                    if (rr >= 0 && rr < 64) rowRank[rr] = (u16)((blk << 6) | bit);
                    int cc = pos - j0;
                    if (cc >= 0 && cc < 64) colRank[cc] = (u16)((blk << 6) | bit);
                    ++pos;
                    if (pos >= cE && pos >= rE) break;
                }
            }
        }
    }
    __syncthreads();

    /* load boxes (sentinels beyond Kc) */
    float4 rb, cb;
    float ra, ca;
    if (r < Kc) {
        rb = boxr[rowRank[lane]];
        ra = (rb.z - rb.x + 1.0f) * (rb.w - rb.y + 1.0f);
    } else {
        rb = make_float4(-3e30f, -3e30f, -3e30f, -3e30f);
        ra = 3e38f;
    }
    if (j0 + lane < Kc) {
        cb = boxr[colRank[lane]];
        ca = (cb.z - cb.x + 1.0f) * (cb.w - cb.y + 1.0f);
    } else {
        cb = make_float4(-3e30f, -3e30f, -3e30f, -3e30f);
        ca = 3e38f;
    }
    u64 word = 0ull;
    #pragma unroll 8
    for (int q = 0; q < 64; ++q) {
        float cbx = __shfl(cb.x, q);
        float cby = __shfl(cb.y, q);
        float cbz = __shfl(cb.z, q);
        float cbw = __shfl(cb.w, q);
        float cav = __shfl(ca, q);
        float ih = fminf(rb.z, cbz) - fmaxf(rb.x, cbx) + 1.0f;
        float iw = fminf(rb.w, cbw) - fmaxf(rb.y, cby) + 1.0f;
        ih = fmaxf(ih, 0.0f); iw = fmaxf(iw, 0.0f);
        /* iou>=0.5 <=> 3*inter >= ai+aj */
        bool o = (3.0f * ih * iw >= ra + cav) && ((j0 + q) > r);
        if (o) word |= (1ull << q);
    }
    mg[r * MSTRIDE + c] = word;
}

/* 6: self-ranking per-group serial greedy (A2+A3 inlined; no prep kernel). */
__global__ __launch_bounds__(512) void greedy_kernel(const u32* __restrict__ gbits,
                                                     const u64* __restrict__ maskg,
                                                     float* __restrict__ out) {
    __shared__ u64 maskm[KMAX * MSTRIDE + 64];   /* 56.8 KB */
    __shared__ u16 grank[KMAX];
    __shared__ int bpre[96];
    __shared__ int sK;
    int g = blockIdx.x, t = threadIdx.x, lane = t & 63, wv = t >> 6;
    const u32* rb32 = gbits + g * 192;

    if (t < 64) {
        u64 w0 = (u64)rb32[2 * lane] | ((u64)rb32[2 * lane + 1] << 32);
        u64 w1 = (lane < NBLK - 64)
                 ? ((u64)rb32[128 + 2 * lane] | ((u64)rb32[129 + 2 * lane] << 32)) : 0ull;
        int c0 = (int)__popcll(w0), c1 = (int)__popcll(w1);
        int i0 = c0, i1 = c1;
        #pragma unroll
        for (int off = 1; off < 64; off <<= 1) {
            int a = __shfl_up(i0, off); if (lane >= off) i0 += a;
            int b = __shfl_up(i1, off); if (lane >= off) i1 += b;
        }
        int tot0 = __shfl(i0, 63), tot1 = __shfl(i1, 63);
        bpre[lane] = i0 - c0;
        if (lane < 32) bpre[64 + lane] = tot0 + ((lane < NBLK - 64) ? (i1 - c1) : 0);
        if (lane == 0) sK = tot0 + tot1;
    }
    __syncthreads();
    int K = sK;
    if (K == 0) return;
    int Kc = (K < KMAX) ? K : KMAX;
    int W = (Kc + 63) >> 6;

    for (int blk = wv; blk < NBLK; blk += 8) {
        u64 wmask = (u64)rb32[2 * blk] | ((u64)rb32[2 * blk + 1] << 32);
        if ((wmask >> lane) & 1ull) {
            int pos = bpre[blk] + (int)__popcll(wmask & ((1ull << lane) - 1ull));
            if (pos < KMAX) grank[pos] = (u16)((blk << 6) | lane);
        }
    }
    const u64* mg = maskg + (size_t)g * (KMAX * MSTRIDE);
    int nw = Kc * MSTRIDE;
    for (int m = t; m < nw; m += 512) maskm[m] = mg[m];
    for (int m = nw + t; m < nw + 64; m += 512) maskm[m] = 0ull;
    __syncthreads();

    if (t >= 64) return;
    u64 remv = 0ull;
    for (int w = 0; w < W; ++w) {
        int r0 = w << 6;
        int rend = Kc - r0; if (rend > 64) rend = 64;
        u64 curw = __shfl(remv, w);
        u64 kb = 0ull;
        for (int b0 = 0; b0 < rend; b0 += 8) {
            int n = rend - b0; if (n > 8) n = 8;
            u64 mrow[8], dg[8];
            #pragma unroll
            for (int j = 0; j < 8; ++j) {
                int rr = r0 + b0 + ((j < n) ? j : 0);
                mrow[j] = maskm[rr * MSTRIDE + lane];   /* +64 pad covers overrun */
                dg[j]   = maskm[rr * MSTRIDE + w];      /* uniform: broadcast */
            }
            #pragma unroll
            for (int j = 0; j < 8; ++j) {
                if (j < n) {
                    int b = b0 + j;
                    u64 km = ((curw >> b) & 1ull) ? 0ull : ~0ull;
                    curw |= dg[j] & km;
                    remv |= mrow[j] & km;
                    kb |= km & (1ull << b);
                }
            }
        }
        if (lane < rend)
            out[(int)grank[r0 + lane] * 6 + 5] = ((kb >> lane) & 1ull) ? 1.0f : 0.0f;
    }
}

extern "C" void kernel_launch(void* const* d_in, const int* in_sizes, int n_in,
                              void* d_out, int out_size, void* d_ws, size_t ws_size,
                              hipStream_t stream) {
    const float*  probs    = (const float*)d_in[0];
    const float4* deltas4  = (const float4*)d_in[1];
    const float4* anchors4 = (const float4*)d_in[2];
    int n_prop = in_sizes[1] / 4;   /* 522240 */
    int n_anch = in_sizes[2] / 4;   /* 65280  */

    char* ws = (char*)d_ws;
    u32* ctr      = (u32*)(ws + CTR_OFF);
    u32* fineh    = (u32*)(ws + FINEH_OFF);
    u32* bcnt     = (u32*)(ws + BCNT_OFF);
    u32* gbits    = (u32*)(ws + GBITS_OFF);
    u64* cand     = (u64*)(ws + CAND_OFF);
    float4* boxr  = (float4*)(ws + BOXR_OFF);
    u64* maskg    = (u64*)(ws + MASKG_OFF);
    u32* base     = (u32*)(ws + BASE_OFF);
    float* out    = (float*)d_out;

    zero_kernel<<<64, 256, 0, stream>>>((u32*)ws);
    hist_kernel<<<NHB, 1024, 0, stream>>>((const float4*)probs, fineh, n_prop);
    pivot_kernel<<<1, 1024, 0, stream>>>((const float4*)probs, fineh, ctr, base, n_prop);
    scatter_kernel<<<256, 256, 0, stream>>>((const float4*)probs, ctr, base, bcnt,
                                            cand, n_prop);
    rankdecode_kernel<<<CANDMAX / 256, 256, 0, stream>>>(cand, ctr, base, bcnt,
                                                         deltas4, anchors4,
                                                         boxr, gbits, out, n_anch);
    mask_kernel<<<dim3(MTILE, NGRP), 64, 0, stream>>>(gbits, boxr, maskg);
    greedy_kernel<<<NGRP, 512, 0, stream>>>(gbits, maskg, out);
}